// Round 5
// baseline (1114.058 us; speedup 1.0000x reference)
//
#include <hip/hip_runtime.h>
#include <math.h>

#define BB 4
#define CC 128
#define HH 64
#define WW 64
#define LL 4096            // H*W
#define LL2 ((size_t)LL*LL)
#define EPSF 1e-7f
#define NCH 16             // softmax stats chunks over l

typedef __attribute__((ext_vector_type(8))) short s8v;           // 8 bf16 (4 VGPRs)
typedef __attribute__((ext_vector_type(4))) float f4v;           // 4 fp32
typedef __attribute__((ext_vector_type(4))) unsigned short u4v;  // 4 bf16 (8B)

struct f4u { float v[4]; };

__device__ __forceinline__ ushort f2bf(float f) {
    union { float f; unsigned u; } x; x.f = f;
    unsigned r = x.u + 0x7FFFu + ((x.u >> 16) & 1u);   // RNE
    return (ushort)(r >> 16);
}
__device__ __forceinline__ float bf2f(ushort u) {
    union { unsigned u; float f; } x; x.u = ((unsigned)u) << 16;
    return x.f;
}

// ---------- K1: per-position channel sums ----------
__global__ void prep_kernel(const float* __restrict__ fg, const float* __restrict__ mask,
                            float* __restrict__ Sfg, float* __restrict__ Sbg,
                            float* __restrict__ Qq) {
    int g = blockIdx.x * 256 + threadIdx.x;       // B*L threads
    int b = g >> 12, p = g & (LL - 1);
    float mval = mask[g];
    float s = 0.f, sb = 0.f, q = 0.f;
    const float* f = fg + (size_t)b * CC * LL + p;
    for (int c = 0; c < CC; ++c) {
        float v = f[(size_t)c * LL];
        s += v;
        float bv = v * (1.f - mval);
        sb += bv;
        q += bv * bv;
    }
    Sfg[g] = s; Sbg[g] = sb; Qq[g] = q;
}

// ---------- K2: inorm[l] = 1/norm, SfgTap[p] = sum of valid Sfg taps ----------
__global__ void norm_kernel(const float* __restrict__ Sfg, const float* __restrict__ Sbg,
                            const float* __restrict__ Qq, float* __restrict__ inorm,
                            float* __restrict__ SfgTap) {
    int g = blockIdx.x * 256 + threadIdx.x;       // B*L
    int b = g >> 12, l = g & (LL - 1);
    int i = l >> 6, j = l & 63;
    float n2 = 9.f * CC * EPSF * EPSF;
    float st = 0.f;
    for (int di = -1; di <= 1; ++di)
        for (int dj = -1; dj <= 1; ++dj) {
            int ii = i + di, jj = j + dj;
            if (ii >= 0 && ii < HH && jj >= 0 && jj < WW) {
                int idx = (b << 12) + (ii << 6) + jj;
                n2 += Qq[idx] + 2.f * EPSF * Sbg[idx];
                st += Sfg[idx];
            }
        }
    inorm[g] = 1.f / sqrtf(n2);
    SfgTap[g] = st;
}

// ---------- K2b: per-sample bf16 copies: fgT/bgT [L][C] (transposed), bgH [C][L] ----------
__global__ __launch_bounds__(256) void transpose_kernel(const float* __restrict__ fgb,
                                                        const float* __restrict__ maskb,
                                                        ushort* __restrict__ fgT,
                                                        ushort* __restrict__ bgT,
                                                        ushort* __restrict__ bgH) {
    __shared__ float tile[64][65];
    int l0 = blockIdx.x * 64, c0 = blockIdx.y * 64;
    int tid = threadIdx.x, col = tid & 63, r0 = tid >> 6;
    for (int r = r0; r < 64; r += 4) {
        float v = fgb[(size_t)(c0 + r) * LL + l0 + col];
        tile[r][col] = v;
        bgH[(size_t)(c0 + r) * LL + l0 + col] = f2bf(v * (1.f - maskb[l0 + col]));
    }
    __syncthreads();
    for (int idx = tid; idx < 4096; idx += 256) {
        int row = idx >> 6;     // l offset
        int c = idx & 63;       // c offset
        float v = tile[c][row];
        size_t o = (size_t)(l0 + row) * CC + c0 + c;
        fgT[o] = f2bf(v);
        bgT[o] = f2bf(v * (1.f - maskb[l0 + row]));
    }
}

// ---------- K3: M = bg^T @ fg via MFMA bf16. A=bgT[L][C], B^T=fgT[L][C] ----------
__global__ __launch_bounds__(256) void gemm_M_mfma(const ushort* __restrict__ bgT,
                                                   const ushort* __restrict__ fgT,
                                                   float* __restrict__ M) {
    int lt = blockIdx.y, pt = blockIdx.x;            // 32x32 tiles of 128x128
    int wid = threadIdx.x >> 6, lane = threadIdx.x & 63;
    int wm = wid >> 1, wn = wid & 1;                 // 2x2 waves
    int lm = lane & 15, lk = lane >> 4;
    f4v acc[4][4] = {};
    int arow = lt * 128 + wm * 64 + lm;
    int brow = pt * 128 + wn * 64 + lm;
    for (int k0 = 0; k0 < CC; k0 += 32) {
        s8v a[4], bq[4];
        #pragma unroll
        for (int f = 0; f < 4; ++f)
            a[f] = *(const s8v*)(bgT + (size_t)(arow + f * 16) * CC + k0 + lk * 8);
        #pragma unroll
        for (int f = 0; f < 4; ++f)
            bq[f] = *(const s8v*)(fgT + (size_t)(brow + f * 16) * CC + k0 + lk * 8);
        #pragma unroll
        for (int mi = 0; mi < 4; ++mi)
            #pragma unroll
            for (int ni = 0; ni < 4; ++ni)
                acc[mi][ni] = __builtin_amdgcn_mfma_f32_16x16x32_bf16(a[mi], bq[ni], acc[mi][ni], 0, 0, 0);
    }
    #pragma unroll
    for (int mi = 0; mi < 4; ++mi)
        #pragma unroll
        for (int ni = 0; ni < 4; ++ni)
            #pragma unroll
            for (int r = 0; r < 4; ++r)
                M[(size_t)(lt * 128 + wm * 64 + mi * 16 + lk * 4 + r) * LL
                  + pt * 128 + wn * 64 + ni * 16 + lm] = acc[mi][ni][r];
}

// ---------- K4: SB[l,:] = box_p( (9-tap diag-sum of M + EPS*SfgTap)*inorm[l] ), 4-wide ----------
__global__ __launch_bounds__(256) void scoresbox_kernel(const float* __restrict__ M,
                                                        const float* __restrict__ SfgTap,
                                                        const float* __restrict__ inorm,
                                                        float* __restrict__ SB, int bofs) {
    __shared__ float srow[LL + 136];
    float* sr = srow + 68;
    int l = blockIdx.x;
    int i = l >> 6, j = l & 63;
    float inl = inorm[bofs + l];
    for (int it = 0; it < 4; ++it) {
        int p = 4 * (threadIdx.x + it * 256);
        int y = p >> 6, x0 = p & 63;
        bool e0 = (x0 == 0), e3 = (x0 == 60);
        f4u t = *(const f4u*)(SfgTap + bofs + p);
        float s0 = EPSF * t.v[0], s1 = EPSF * t.v[1], s2 = EPSF * t.v[2], s3 = EPSF * t.v[3];
        #pragma unroll
        for (int di = -1; di <= 1; ++di) {
            int ii = i + di, yy = y + di;
            if ((unsigned)ii >= HH || (unsigned)yy >= HH) continue;
            #pragma unroll
            for (int dj = -1; dj <= 1; ++dj) {
                int jj = j + dj;
                if ((unsigned)jj >= WW) continue;
                int D = di * 64 + dj;
                f4u v = *(const f4u*)(M + (size_t)(l + D) * LL + (p + D));
                float v0 = v.v[0], v3 = v.v[3];
                if (dj == -1) v0 = e0 ? 0.f : v0;
                if (dj == 1)  v3 = e3 ? 0.f : v3;
                s0 += v0; s1 += v.v[1]; s2 += v.v[2]; s3 += v3;
            }
        }
        f4u o; o.v[0] = s0 * inl; o.v[1] = s1 * inl; o.v[2] = s2 * inl; o.v[3] = s3 * inl;
        *(f4u*)(sr + p) = o;
    }
    __syncthreads();
    for (int it = 0; it < 4; ++it) {
        int p = 4 * (threadIdx.x + it * 256);
        int y = p >> 6, x0 = p & 63;
        bool e0 = (x0 == 0), e3 = (x0 == 60);
        float b0 = 0.f, b1 = 0.f, b2 = 0.f, b3 = 0.f;
        #pragma unroll
        for (int gy = -1; gy <= 1; ++gy) {
            int yy = y + gy;
            if ((unsigned)yy >= HH) continue;
            int base = (yy << 6) + x0;
            float m1 = sr[base - 1], c0 = sr[base], c1 = sr[base + 1];
            float c2 = sr[base + 2], c3 = sr[base + 3], p4 = sr[base + 4];
            b0 += (e0 ? 0.f : m1) + c0 + c1;
            b1 += c0 + c1 + c2;
            b2 += c1 + c2 + c3;
            b3 += c2 + c3 + (e3 ? 0.f : p4);
        }
        f4u o; o.v[0] = b0; o.v[1] = b1; o.v[2] = b2; o.v[3] = b3;
        *(f4u*)(SB + (size_t)l * LL + p) = o;
    }
}

// ---------- K5: per-column online softmax stats over SB ----------
__global__ __launch_bounds__(256) void stats2_kernel(const float* __restrict__ SB,
                                                     const float* __restrict__ inorm,
                                                     float* __restrict__ maxc, float* __restrict__ sumc,
                                                     float* __restrict__ wsumc, int bofs) {
    int pt = blockIdx.x, ch = blockIdx.y;
    int lane = threadIdx.x & 63, grp = threadIdx.x >> 6;
    int p = pt * 64 + lane;
    float mx = -1e30f, se = 0.f, ws = 0.f;
    int l0 = ch * (LL / NCH);
    for (int l = l0 + grp; l < l0 + (LL / NCH); l += 4) {
        float bs = SB[(size_t)l * LL + p];
        float in = inorm[bofs + l];
        float nm = fmaxf(mx, bs);
        float r1 = __expf(mx - nm), r2 = __expf(bs - nm);
        se = se * r1 + r2;
        ws = ws * r1 + r2 * in;
        mx = nm;
    }
    __shared__ float smx[4][64], sse[4][64], sws[4][64];
    smx[grp][lane] = mx; sse[grp][lane] = se; sws[grp][lane] = ws;
    __syncthreads();
    if (grp == 0) {
        for (int k = 1; k < 4; ++k) {
            float m2 = smx[k][lane], s2 = sse[k][lane], w2 = sws[k][lane];
            float nm = fmaxf(mx, m2);
            float r1 = __expf(mx - nm), r2 = __expf(m2 - nm);
            se = se * r1 + s2 * r2;
            ws = ws * r1 + w2 * r2;
            mx = nm;
        }
        int idx = ch * LL + p;
        maxc[idx] = mx; sumc[idx] = se; wsumc[idx] = ws;
    }
}

// ---------- K5b: combine chunk stats: adj = max + log(sum); Tp from box of ws/se ----------
__global__ __launch_bounds__(1024) void combine_ttap_kernel(const float* __restrict__ maxc,
                                                            const float* __restrict__ sumc,
                                                            const float* __restrict__ wsumc,
                                                            float* __restrict__ adj,
                                                            float* __restrict__ Tp) {
    __shared__ float bsum[LL];
    int t = threadIdx.x;
    for (int k = 0; k < 4; ++k) {
        int p = t + k * 1024;
        float mx = -1e30f, se = 0.f, ws = 0.f;
        for (int ch = 0; ch < NCH; ++ch) {
            int idx = ch * LL + p;
            float m2 = maxc[idx], s2 = sumc[idx], w2 = wsumc[idx];
            float nm = fmaxf(mx, m2);
            float r1 = __expf(mx - nm), r2 = __expf(m2 - nm);
            se = se * r1 + s2 * r2;
            ws = ws * r1 + w2 * r2;
            mx = nm;
        }
        adj[p] = mx + __logf(se);
        bsum[p] = ws / se;
    }
    __syncthreads();
    for (int k = 0; k < 4; ++k) {
        int p = t + k * 1024;
        int y = p >> 6, x = p & 63;
        float tt = 0.f;
        for (int gy = -1; gy <= 1; ++gy) {
            int yy = y + gy;
            if (yy < 0 || yy >= HH) continue;
            for (int gx = -1; gx <= 1; ++gx) {
                int xx = x + gx;
                if (xx < 0 || xx >= WW) continue;
                tt += bsum[(yy << 6) + xx];
            }
        }
        Tp[p] = tt;
    }
}

// ---------- K7: Nnh[l,p] (bf16) = 9-tap diag sum of exp(SB - adj[p'])*inorm[l'] ----------
__global__ __launch_bounds__(256) void bnfuse_kernel(const float* __restrict__ SB,
                                                     const float* __restrict__ adj,
                                                     const float* __restrict__ inorm,
                                                     ushort* __restrict__ Nnh, int bofs) {
    int l = blockIdx.x;
    int i = l >> 6, j = l & 63;
    for (int it = 0; it < 4; ++it) {
        int p = 4 * (threadIdx.x + it * 256);
        int y = p >> 6, x0 = p & 63;
        bool e0 = (x0 == 0), e3 = (x0 == 60);
        float a0 = 0.f, a1 = 0.f, a2 = 0.f, a3 = 0.f;
        #pragma unroll
        for (int di = -1; di <= 1; ++di) {
            int ii = i + di, yy = y + di;
            if ((unsigned)ii >= HH || (unsigned)yy >= HH) continue;
            #pragma unroll
            for (int dj = -1; dj <= 1; ++dj) {
                int jj = j + dj;
                if ((unsigned)jj >= WW) continue;
                int D = di * 64 + dj;
                f4u s = *(const f4u*)(SB + (size_t)(l + D) * LL + (p + D));
                f4u av = *(const f4u*)(adj + p + D);
                float inl = inorm[bofs + l + D];
                float t0 = __expf(s.v[0] - av.v[0]) * inl;
                float t1 = __expf(s.v[1] - av.v[1]) * inl;
                float t2 = __expf(s.v[2] - av.v[2]) * inl;
                float t3 = __expf(s.v[3] - av.v[3]) * inl;
                if (dj == -1) t0 = e0 ? 0.f : t0;
                if (dj == 1)  t3 = e3 ? 0.f : t3;
                a0 += t0; a1 += t1; a2 += t2; a3 += t3;
            }
        }
        u4v o;
        o[0] = f2bf(a0); o[1] = f2bf(a1); o[2] = f2bf(a2); o[3] = f2bf(a3);
        *(u4v*)(Nnh + (size_t)l * LL + p) = o;
    }
}

// ---------- K8: bf16 transpose Nnh[l][p] -> NnT[p][l] ----------
__global__ __launch_bounds__(256) void transpose16_kernel(const ushort* __restrict__ Nnh,
                                                          ushort* __restrict__ NnT) {
    __shared__ ushort tile[64][72];
    int l0 = blockIdx.x * 64, p0 = blockIdx.y * 64;
    int t = threadIdx.x;
    int col = (t & 15) * 4, row = t >> 4;           // 16 rows per pass
    #pragma unroll
    for (int pass = 0; pass < 4; ++pass) {
        int r = pass * 16 + row;
        *(u4v*)&tile[r][col] = *(const u4v*)(Nnh + (size_t)(l0 + r) * LL + p0 + col);
    }
    __syncthreads();
    #pragma unroll
    for (int pass = 0; pass < 4; ++pass) {
        int r = pass * 16 + row;                    // p-local
        u4v v;
        #pragma unroll
        for (int i2 = 0; i2 < 4; ++i2)
            v[i2] = tile[col + i2][r];
        *(u4v*)(NnT + (size_t)(p0 + r) * LL + l0 + col) = v;
    }
}

// ---------- K9: rec = bgH @ NnT^T via MFMA, fused final epilogue ----------
// grid 128 blocks (p-tiles of 32); 4 waves stacked on c (wave w: c in [w*32, w*32+32))
__global__ __launch_bounds__(256) void gemm_out_mfma(const ushort* __restrict__ bgH,
                                                     const ushort* __restrict__ NnT,
                                                     const float* __restrict__ Tp,
                                                     const float* __restrict__ fgb,
                                                     const float* __restrict__ maskb,
                                                     float* __restrict__ outb) {
    int pt = blockIdx.x;
    int wid = threadIdx.x >> 6, lane = threadIdx.x & 63;
    int lm = lane & 15, lk = lane >> 4;
    f4v acc[2][2] = {};
    int arow = wid * 32 + lm;        // c
    int brow = pt * 32 + lm;         // p
    #pragma unroll 4
    for (int k0 = 0; k0 < LL; k0 += 32) {
        s8v a0 = *(const s8v*)(bgH + (size_t)arow * LL + k0 + lk * 8);
        s8v a1 = *(const s8v*)(bgH + (size_t)(arow + 16) * LL + k0 + lk * 8);
        s8v b0 = *(const s8v*)(NnT + (size_t)brow * LL + k0 + lk * 8);
        s8v b1 = *(const s8v*)(NnT + (size_t)(brow + 16) * LL + k0 + lk * 8);
        acc[0][0] = __builtin_amdgcn_mfma_f32_16x16x32_bf16(a0, b0, acc[0][0], 0, 0, 0);
        acc[0][1] = __builtin_amdgcn_mfma_f32_16x16x32_bf16(a0, b1, acc[0][1], 0, 0, 0);
        acc[1][0] = __builtin_amdgcn_mfma_f32_16x16x32_bf16(a1, b0, acc[1][0], 0, 0, 0);
        acc[1][1] = __builtin_amdgcn_mfma_f32_16x16x32_bf16(a1, b1, acc[1][1], 0, 0, 0);
    }
    #pragma unroll
    for (int mi = 0; mi < 2; ++mi)
        #pragma unroll
        for (int ni = 0; ni < 2; ++ni)
            #pragma unroll
            for (int r = 0; r < 4; ++r) {
                int c = wid * 32 + mi * 16 + lk * 4 + r;
                int p = pt * 32 + ni * 16 + lm;
                float rec = acc[mi][ni][r] + EPSF * Tp[p];
                float mv = maskb[p];
                outb[(size_t)c * LL + p] = rec * mv * (1.f / 9.f) + fgb[(size_t)c * LL + p] * (1.f - mv);
            }
}

extern "C" void kernel_launch(void* const* d_in, const int* in_sizes, int n_in,
                              void* d_out, int out_size, void* d_ws, size_t ws_size,
                              hipStream_t stream) {
    const float* fg = (const float*)d_in[0];     // [B,C,H,W]
    const float* mask = (const float*)d_in[1];   // [B,1,H,W]
    float* out = (float*)d_out;
    float* ws = (float*)d_ws;

    // ws layout (~133 MiB, same as round-4 proven size)
    float* Sfg = ws;                                 // B*LL each:
    float* Sbg = Sfg + BB * LL;
    float* Qq = Sbg + BB * LL;
    float* inorm = Qq + BB * LL;
    float* SfgTap = inorm + BB * LL;
    float* maxc = SfgTap + BB * LL;                  // NCH*LL each:
    float* sumc = maxc + NCH * LL;
    float* wsumc = sumc + NCH * LL;
    float* adj = wsumc + NCH * LL;                   // LL each:
    float* Tp = adj + LL;
    ushort* bgH = (ushort*)(Tp + LL);                // B*CC*LL ushorts (4 MiB)
    float* bufA = (float*)(bgH + (size_t)BB * CC * LL);   // LL2 (M, then Nnh+NnT)
    float* bufB = bufA + LL2;                        // LL2 (SB)
    // per-sample transposed bf16 operand tiles live in bufB tail (dead until scoresbox):
    ushort* bgT = (ushort*)(bufB + 8 * 1024 * 1024);
    ushort* fgT = bgT + (size_t)LL * CC;
    // after scoresbox, M (bufA) is dead -> reuse for Nnh (32 MB) + NnT (32 MB):
    ushort* Nnh = (ushort*)bufA;
    ushort* NnT = (ushort*)(bufA + 8 * 1024 * 1024);

    prep_kernel<<<BB * LL / 256, 256, 0, stream>>>(fg, mask, Sfg, Sbg, Qq);
    norm_kernel<<<BB * LL / 256, 256, 0, stream>>>(Sfg, Sbg, Qq, inorm, SfgTap);

    for (int b = 0; b < BB; ++b) {
        const float* fgb = fg + (size_t)b * CC * LL;
        const float* mb = mask + (size_t)b * LL;
        ushort* bgHb = bgH + (size_t)b * CC * LL;
        int bofs = b * LL;

        transpose_kernel<<<dim3(64, 2), 256, 0, stream>>>(fgb, mb, fgT, bgT, bgHb);
        gemm_M_mfma<<<dim3(32, 32), 256, 0, stream>>>(bgT, fgT, bufA);
        scoresbox_kernel<<<LL, 256, 0, stream>>>(bufA, SfgTap, inorm, bufB, bofs);
        stats2_kernel<<<dim3(64, NCH), 256, 0, stream>>>(bufB, inorm, maxc, sumc, wsumc, bofs);
        combine_ttap_kernel<<<1, 1024, 0, stream>>>(maxc, sumc, wsumc, adj, Tp);
        bnfuse_kernel<<<LL, 256, 0, stream>>>(bufB, adj, inorm, Nnh, bofs);
        transpose16_kernel<<<dim3(64, 64), 256, 0, stream>>>(Nnh, NnT);
        gemm_out_mfma<<<128, 256, 0, stream>>>(bgHb, NnT, Tp, fgb, mb, out + (size_t)b * CC * LL);
    }
}

// Round 6
// 893.062 us; speedup vs baseline: 1.2475x; 1.2475x over previous
//
#include <hip/hip_runtime.h>
#include <math.h>

#define BB 4
#define CC 128
#define HH 64
#define WW 64
#define LL 4096            // H*W
#define LL2 ((size_t)LL*LL)
#define EPSF 1e-7f
#define NCH 16             // softmax stats chunks over l
#define KS 8               // gemm_out k-slabs

typedef __attribute__((ext_vector_type(8))) short s8v;           // 8 bf16 (4 VGPRs)
typedef __attribute__((ext_vector_type(4))) float f4v;           // 4 fp32
typedef __attribute__((ext_vector_type(4))) unsigned short u4v;  // 4 bf16 (8B)

struct f4u { float v[4]; };

__device__ __forceinline__ ushort f2bf(float f) {
    union { float f; unsigned u; } x; x.f = f;
    unsigned r = x.u + 0x7FFFu + ((x.u >> 16) & 1u);   // RNE
    return (ushort)(r >> 16);
}
__device__ __forceinline__ float bf2f(ushort u) {
    union { unsigned u; float f; } x; x.u = ((unsigned)u) << 16;
    return x.f;
}

// ---------- K1: per-position channel sums ----------
__global__ void prep_kernel(const float* __restrict__ fg, const float* __restrict__ mask,
                            float* __restrict__ Sfg, float* __restrict__ Sbg,
                            float* __restrict__ Qq) {
    int g = blockIdx.x * 256 + threadIdx.x;       // B*L threads
    int b = g >> 12, p = g & (LL - 1);
    float mval = mask[g];
    float s = 0.f, sb = 0.f, q = 0.f;
    const float* f = fg + (size_t)b * CC * LL + p;
    for (int c = 0; c < CC; ++c) {
        float v = f[(size_t)c * LL];
        s += v;
        float bv = v * (1.f - mval);
        sb += bv;
        q += bv * bv;
    }
    Sfg[g] = s; Sbg[g] = sb; Qq[g] = q;
}

// ---------- K2: inorm[l] = 1/norm, SfgTap[p] = sum of valid Sfg taps ----------
__global__ void norm_kernel(const float* __restrict__ Sfg, const float* __restrict__ Sbg,
                            const float* __restrict__ Qq, float* __restrict__ inorm,
                            float* __restrict__ SfgTap) {
    int g = blockIdx.x * 256 + threadIdx.x;       // B*L
    int b = g >> 12, l = g & (LL - 1);
    int i = l >> 6, j = l & 63;
    float n2 = 9.f * CC * EPSF * EPSF;
    float st = 0.f;
    for (int di = -1; di <= 1; ++di)
        for (int dj = -1; dj <= 1; ++dj) {
            int ii = i + di, jj = j + dj;
            if (ii >= 0 && ii < HH && jj >= 0 && jj < WW) {
                int idx = (b << 12) + (ii << 6) + jj;
                n2 += Qq[idx] + 2.f * EPSF * Sbg[idx];
                st += Sfg[idx];
            }
        }
    inorm[g] = 1.f / sqrtf(n2);
    SfgTap[g] = st;
}

// ---------- K2b: per-sample bf16 copies: fgT/bgT [L][C] (transposed), bgH [C][L] ----------
__global__ __launch_bounds__(256) void transpose_kernel(const float* __restrict__ fgb,
                                                        const float* __restrict__ maskb,
                                                        ushort* __restrict__ fgT,
                                                        ushort* __restrict__ bgT,
                                                        ushort* __restrict__ bgH) {
    __shared__ float tile[64][65];
    int l0 = blockIdx.x * 64, c0 = blockIdx.y * 64;
    int tid = threadIdx.x, col = tid & 63, r0 = tid >> 6;
    for (int r = r0; r < 64; r += 4) {
        float v = fgb[(size_t)(c0 + r) * LL + l0 + col];
        tile[r][col] = v;
        bgH[(size_t)(c0 + r) * LL + l0 + col] = f2bf(v * (1.f - maskb[l0 + col]));
    }
    __syncthreads();
    for (int idx = tid; idx < 4096; idx += 256) {
        int row = idx >> 6;     // l offset
        int c = idx & 63;       // c offset
        float v = tile[c][row];
        size_t o = (size_t)(l0 + row) * CC + c0 + c;
        fgT[o] = f2bf(v);
        bgT[o] = f2bf(v * (1.f - maskb[l0 + row]));
    }
}

// ---------- K3: M = bg^T @ fg via MFMA bf16. A=bgT[L][C], B^T=fgT[L][C] ----------
__global__ __launch_bounds__(256) void gemm_M_mfma(const ushort* __restrict__ bgT,
                                                   const ushort* __restrict__ fgT,
                                                   float* __restrict__ M) {
    int lt = blockIdx.y, pt = blockIdx.x;            // 32x32 tiles of 128x128
    int wid = threadIdx.x >> 6, lane = threadIdx.x & 63;
    int wm = wid >> 1, wn = wid & 1;                 // 2x2 waves
    int lm = lane & 15, lk = lane >> 4;
    f4v acc[4][4] = {};
    int arow = lt * 128 + wm * 64 + lm;
    int brow = pt * 128 + wn * 64 + lm;
    for (int k0 = 0; k0 < CC; k0 += 32) {
        s8v a[4], bq[4];
        #pragma unroll
        for (int f = 0; f < 4; ++f)
            a[f] = *(const s8v*)(bgT + (size_t)(arow + f * 16) * CC + k0 + lk * 8);
        #pragma unroll
        for (int f = 0; f < 4; ++f)
            bq[f] = *(const s8v*)(fgT + (size_t)(brow + f * 16) * CC + k0 + lk * 8);
        #pragma unroll
        for (int mi = 0; mi < 4; ++mi)
            #pragma unroll
            for (int ni = 0; ni < 4; ++ni)
                acc[mi][ni] = __builtin_amdgcn_mfma_f32_16x16x32_bf16(a[mi], bq[ni], acc[mi][ni], 0, 0, 0);
    }
    #pragma unroll
    for (int mi = 0; mi < 4; ++mi)
        #pragma unroll
        for (int ni = 0; ni < 4; ++ni)
            #pragma unroll
            for (int r = 0; r < 4; ++r)
                M[(size_t)(lt * 128 + wm * 64 + mi * 16 + lk * 4 + r) * LL
                  + pt * 128 + wn * 64 + ni * 16 + lm] = acc[mi][ni][r];
}

// ---------- K4: SB[l,:] = box_p( (9-tap diag-sum of M + EPS*SfgTap)*inorm[l] ), 4-wide ----------
__global__ __launch_bounds__(256) void scoresbox_kernel(const float* __restrict__ M,
                                                        const float* __restrict__ SfgTap,
                                                        const float* __restrict__ inorm,
                                                        float* __restrict__ SB, int bofs) {
    __shared__ float srow[LL + 136];
    float* sr = srow + 68;
    int l = blockIdx.x;
    int i = l >> 6, j = l & 63;
    float inl = inorm[bofs + l];
    for (int it = 0; it < 4; ++it) {
        int p = 4 * (threadIdx.x + it * 256);
        int y = p >> 6, x0 = p & 63;
        bool e0 = (x0 == 0), e3 = (x0 == 60);
        f4u t = *(const f4u*)(SfgTap + bofs + p);
        float s0 = EPSF * t.v[0], s1 = EPSF * t.v[1], s2 = EPSF * t.v[2], s3 = EPSF * t.v[3];
        #pragma unroll
        for (int di = -1; di <= 1; ++di) {
            int ii = i + di, yy = y + di;
            if ((unsigned)ii >= HH || (unsigned)yy >= HH) continue;
            #pragma unroll
            for (int dj = -1; dj <= 1; ++dj) {
                int jj = j + dj;
                if ((unsigned)jj >= WW) continue;
                int D = di * 64 + dj;
                f4u v = *(const f4u*)(M + (size_t)(l + D) * LL + (p + D));
                float v0 = v.v[0], v3 = v.v[3];
                if (dj == -1) v0 = e0 ? 0.f : v0;
                if (dj == 1)  v3 = e3 ? 0.f : v3;
                s0 += v0; s1 += v.v[1]; s2 += v.v[2]; s3 += v3;
            }
        }
        f4u o; o.v[0] = s0 * inl; o.v[1] = s1 * inl; o.v[2] = s2 * inl; o.v[3] = s3 * inl;
        *(f4u*)(sr + p) = o;
    }
    __syncthreads();
    for (int it = 0; it < 4; ++it) {
        int p = 4 * (threadIdx.x + it * 256);
        int y = p >> 6, x0 = p & 63;
        bool e0 = (x0 == 0), e3 = (x0 == 60);
        float b0 = 0.f, b1 = 0.f, b2 = 0.f, b3 = 0.f;
        #pragma unroll
        for (int gy = -1; gy <= 1; ++gy) {
            int yy = y + gy;
            if ((unsigned)yy >= HH) continue;
            int base = (yy << 6) + x0;
            float m1 = sr[base - 1], c0 = sr[base], c1 = sr[base + 1];
            float c2 = sr[base + 2], c3 = sr[base + 3], p4 = sr[base + 4];
            b0 += (e0 ? 0.f : m1) + c0 + c1;
            b1 += c0 + c1 + c2;
            b2 += c1 + c2 + c3;
            b3 += c2 + c3 + (e3 ? 0.f : p4);
        }
        f4u o; o.v[0] = b0; o.v[1] = b1; o.v[2] = b2; o.v[3] = b3;
        *(f4u*)(SB + (size_t)l * LL + p) = o;
    }
}

// ---------- K5: per-column online softmax stats over SB ----------
__global__ __launch_bounds__(256) void stats2_kernel(const float* __restrict__ SB,
                                                     const float* __restrict__ inorm,
                                                     float* __restrict__ maxc, float* __restrict__ sumc,
                                                     float* __restrict__ wsumc, int bofs) {
    int pt = blockIdx.x, ch = blockIdx.y;
    int lane = threadIdx.x & 63, grp = threadIdx.x >> 6;
    int p = pt * 64 + lane;
    float mx = -1e30f, se = 0.f, ws = 0.f;
    int l0 = ch * (LL / NCH);
    for (int l = l0 + grp; l < l0 + (LL / NCH); l += 4) {
        float bs = SB[(size_t)l * LL + p];
        float in = inorm[bofs + l];
        float nm = fmaxf(mx, bs);
        float r1 = __expf(mx - nm), r2 = __expf(bs - nm);
        se = se * r1 + r2;
        ws = ws * r1 + r2 * in;
        mx = nm;
    }
    __shared__ float smx[4][64], sse[4][64], sws[4][64];
    smx[grp][lane] = mx; sse[grp][lane] = se; sws[grp][lane] = ws;
    __syncthreads();
    if (grp == 0) {
        for (int k = 1; k < 4; ++k) {
            float m2 = smx[k][lane], s2 = sse[k][lane], w2 = sws[k][lane];
            float nm = fmaxf(mx, m2);
            float r1 = __expf(mx - nm), r2 = __expf(m2 - nm);
            se = se * r1 + s2 * r2;
            ws = ws * r1 + w2 * r2;
            mx = nm;
        }
        int idx = ch * LL + p;
        maxc[idx] = mx; sumc[idx] = se; wsumc[idx] = ws;
    }
}

// ---------- K5b: parallel combine: one block per spatial row y; halo-recompute bsum ----------
__global__ __launch_bounds__(192) void combine_ttap_kernel(const float* __restrict__ maxc,
                                                           const float* __restrict__ sumc,
                                                           const float* __restrict__ wsumc,
                                                           float* __restrict__ adj,
                                                           float* __restrict__ Tp) {
    __shared__ float bs[3][64];
    int yb = blockIdx.x;
    int t = threadIdx.x;              // 0..191
    int r = t >> 6, xcol = t & 63;    // r: row offset (yb-1+r)
    int yy = yb - 1 + r;
    float bv = 0.f;
    if ((unsigned)yy < HH) {
        int p = (yy << 6) + xcol;
        float mx = -1e30f, se = 0.f, ws = 0.f;
        for (int ch = 0; ch < NCH; ++ch) {
            int idx = ch * LL + p;
            float m2 = maxc[idx], s2 = sumc[idx], w2 = wsumc[idx];
            float nm = fmaxf(mx, m2);
            float r1 = __expf(mx - nm), r2 = __expf(m2 - nm);
            se = se * r1 + s2 * r2;
            ws = ws * r1 + w2 * r2;
            mx = nm;
        }
        if (r == 1) adj[p] = mx + __logf(se);
        bv = ws / se;
    }
    bs[r][xcol] = bv;
    __syncthreads();
    if (r == 1) {
        float tt = 0.f;
        #pragma unroll
        for (int rr = 0; rr < 3; ++rr) {
            tt += bs[rr][xcol];
            if (xcol > 0) tt += bs[rr][xcol - 1];
            if (xcol < 63) tt += bs[rr][xcol + 1];
        }
        Tp[(yb << 6) + xcol] = tt;
    }
}

// ---------- K7: Nnh[l,p] (bf16) = 9-tap diag sum of exp(SB - adj[p'])*inorm[l'] ----------
__global__ __launch_bounds__(256) void bnfuse_kernel(const float* __restrict__ SB,
                                                     const float* __restrict__ adj,
                                                     const float* __restrict__ inorm,
                                                     ushort* __restrict__ Nnh, int bofs) {
    int l = blockIdx.x;
    int i = l >> 6, j = l & 63;
    for (int it = 0; it < 4; ++it) {
        int p = 4 * (threadIdx.x + it * 256);
        int y = p >> 6, x0 = p & 63;
        bool e0 = (x0 == 0), e3 = (x0 == 60);
        float a0 = 0.f, a1 = 0.f, a2 = 0.f, a3 = 0.f;
        #pragma unroll
        for (int di = -1; di <= 1; ++di) {
            int ii = i + di, yy = y + di;
            if ((unsigned)ii >= HH || (unsigned)yy >= HH) continue;
            #pragma unroll
            for (int dj = -1; dj <= 1; ++dj) {
                int jj = j + dj;
                if ((unsigned)jj >= WW) continue;
                int D = di * 64 + dj;
                f4u s = *(const f4u*)(SB + (size_t)(l + D) * LL + (p + D));
                f4u av = *(const f4u*)(adj + p + D);
                float inl = inorm[bofs + l + D];
                float t0 = __expf(s.v[0] - av.v[0]) * inl;
                float t1 = __expf(s.v[1] - av.v[1]) * inl;
                float t2 = __expf(s.v[2] - av.v[2]) * inl;
                float t3 = __expf(s.v[3] - av.v[3]) * inl;
                if (dj == -1) t0 = e0 ? 0.f : t0;
                if (dj == 1)  t3 = e3 ? 0.f : t3;
                a0 += t0; a1 += t1; a2 += t2; a3 += t3;
            }
        }
        u4v o;
        o[0] = f2bf(a0); o[1] = f2bf(a1); o[2] = f2bf(a2); o[3] = f2bf(a3);
        *(u4v*)(Nnh + (size_t)l * LL + p) = o;
    }
}

// ---------- K8: bf16 transpose Nnh[l][p] -> NnT[p][l] ----------
__global__ __launch_bounds__(256) void transpose16_kernel(const ushort* __restrict__ Nnh,
                                                          ushort* __restrict__ NnT) {
    __shared__ ushort tile[64][72];
    int l0 = blockIdx.x * 64, p0 = blockIdx.y * 64;
    int t = threadIdx.x;
    int col = (t & 15) * 4, row = t >> 4;           // 16 rows per pass
    #pragma unroll
    for (int pass = 0; pass < 4; ++pass) {
        int r = pass * 16 + row;
        *(u4v*)&tile[r][col] = *(const u4v*)(Nnh + (size_t)(l0 + r) * LL + p0 + col);
    }
    __syncthreads();
    #pragma unroll
    for (int pass = 0; pass < 4; ++pass) {
        int r = pass * 16 + row;                    // p-local
        u4v v;
        #pragma unroll
        for (int i2 = 0; i2 < 4; ++i2)
            v[i2] = tile[col + i2][r];
        *(u4v*)(NnT + (size_t)(p0 + r) * LL + l0 + col) = v;
    }
}

// ---------- K9a: partial rec = bgH @ NnT^T over a k-slab, MFMA ----------
// grid (64 p-tiles of 64, KS k-slabs of 512); 4 waves: wm=c-half(64), wn=p-half(32)
__global__ __launch_bounds__(256) void gemm_out_part_mfma(const ushort* __restrict__ bgH,
                                                          const ushort* __restrict__ NnT,
                                                          float* __restrict__ part) {
    int pt = blockIdx.x, ks = blockIdx.y;
    int wid = threadIdx.x >> 6, lane = threadIdx.x & 63;
    int wm = wid >> 1, wn = wid & 1;
    int lm = lane & 15, lk = lane >> 4;
    f4v acc[4][2] = {};
    int arow = wm * 64 + lm;          // c
    int brow = pt * 64 + wn * 32 + lm; // p
    int kbeg = ks * (LL / KS);
    #pragma unroll 2
    for (int k0 = kbeg; k0 < kbeg + LL / KS; k0 += 32) {
        s8v a[4], bq[2];
        #pragma unroll
        for (int f = 0; f < 4; ++f)
            a[f] = *(const s8v*)(bgH + (size_t)(arow + f * 16) * LL + k0 + lk * 8);
        #pragma unroll
        for (int f = 0; f < 2; ++f)
            bq[f] = *(const s8v*)(NnT + (size_t)(brow + f * 16) * LL + k0 + lk * 8);
        #pragma unroll
        for (int mi = 0; mi < 4; ++mi)
            #pragma unroll
            for (int ni = 0; ni < 2; ++ni)
                acc[mi][ni] = __builtin_amdgcn_mfma_f32_16x16x32_bf16(a[mi], bq[ni], acc[mi][ni], 0, 0, 0);
    }
    #pragma unroll
    for (int mi = 0; mi < 4; ++mi)
        #pragma unroll
        for (int ni = 0; ni < 2; ++ni)
            #pragma unroll
            for (int r = 0; r < 4; ++r)
                part[((size_t)ks * CC + wm * 64 + mi * 16 + lk * 4 + r) * LL
                     + pt * 64 + wn * 32 + ni * 16 + lm] = acc[mi][ni][r];
}

// ---------- K9b: combine slabs + epilogue ----------
__global__ void epilogue_kernel(const float* __restrict__ part, const float* __restrict__ Tp,
                                const float* __restrict__ fgb, const float* __restrict__ maskb,
                                float* __restrict__ outb) {
    int g = blockIdx.x * 256 + threadIdx.x;   // C*L
    int p = g & 4095;
    float acc = 0.f;
    for (int ks = 0; ks < KS; ++ks)
        acc += part[(size_t)ks * CC * LL + g];
    float rec = acc + EPSF * Tp[p];
    float mval = maskb[p];
    outb[g] = rec * mval * (1.f / 9.f) + fgb[g] * (1.f - mval);
}

extern "C" void kernel_launch(void* const* d_in, const int* in_sizes, int n_in,
                              void* d_out, int out_size, void* d_ws, size_t ws_size,
                              hipStream_t stream) {
    const float* fg = (const float*)d_in[0];     // [B,C,H,W]
    const float* mask = (const float*)d_in[1];   // [B,1,H,W]
    float* out = (float*)d_out;
    float* ws = (float*)d_ws;

    // ws layout (~133 MiB, proven size)
    float* Sfg = ws;                                 // B*LL each:
    float* Sbg = Sfg + BB * LL;
    float* Qq = Sbg + BB * LL;
    float* inorm = Qq + BB * LL;
    float* SfgTap = inorm + BB * LL;
    float* maxc = SfgTap + BB * LL;                  // NCH*LL each:
    float* sumc = maxc + NCH * LL;
    float* wsumc = sumc + NCH * LL;
    float* adj = wsumc + NCH * LL;                   // LL each:
    float* Tp = adj + LL;
    ushort* bgH = (ushort*)(Tp + LL);                // B*CC*LL ushorts (4 MiB)
    float* bufA = (float*)(bgH + (size_t)BB * CC * LL);   // LL2 (M, then Nnh+NnT)
    float* bufB = bufA + LL2;                        // LL2 (SB, then part)
    // per-sample transposed bf16 operand tiles live in bufB tail (dead until scoresbox):
    ushort* bgT = (ushort*)(bufB + 8 * 1024 * 1024);
    ushort* fgT = bgT + (size_t)LL * CC;
    // after scoresbox, M (bufA) is dead -> reuse for Nnh (32 MB) + NnT (32 MB):
    ushort* Nnh = (ushort*)bufA;
    ushort* NnT = (ushort*)(bufA + 8 * 1024 * 1024);
    // after bnfuse, SB (bufB) is dead -> reuse for fp32 partials (16 MB):
    float* part = bufB;

    prep_kernel<<<BB * LL / 256, 256, 0, stream>>>(fg, mask, Sfg, Sbg, Qq);
    norm_kernel<<<BB * LL / 256, 256, 0, stream>>>(Sfg, Sbg, Qq, inorm, SfgTap);

    for (int b = 0; b < BB; ++b) {
        const float* fgb = fg + (size_t)b * CC * LL;
        const float* mb = mask + (size_t)b * LL;
        ushort* bgHb = bgH + (size_t)b * CC * LL;
        int bofs = b * LL;

        transpose_kernel<<<dim3(64, 2), 256, 0, stream>>>(fgb, mb, fgT, bgT, bgHb);
        gemm_M_mfma<<<dim3(32, 32), 256, 0, stream>>>(bgT, fgT, bufA);
        scoresbox_kernel<<<LL, 256, 0, stream>>>(bufA, SfgTap, inorm, bufB, bofs);
        stats2_kernel<<<dim3(64, NCH), 256, 0, stream>>>(bufB, inorm, maxc, sumc, wsumc, bofs);
        combine_ttap_kernel<<<64, 192, 0, stream>>>(maxc, sumc, wsumc, adj, Tp);
        bnfuse_kernel<<<LL, 256, 0, stream>>>(bufB, adj, inorm, Nnh, bofs);
        transpose16_kernel<<<dim3(64, 64), 256, 0, stream>>>(Nnh, NnT);
        gemm_out_part_mfma<<<dim3(64, KS), 256, 0, stream>>>(bgHb, NnT, part);
        epilogue_kernel<<<CC * LL / 256, 256, 0, stream>>>(part, Tp, fgb, mb, out + (size_t)b * CC * LL);
    }
}

// Round 7
// 843.016 us; speedup vs baseline: 1.3215x; 1.0594x over previous
//
#include <hip/hip_runtime.h>
#include <math.h>

#define BB 4
#define CC 128
#define HH 64
#define WW 64
#define LL 4096            // H*W
#define LL2 ((size_t)LL*LL)
#define EPSF 1e-7f
#define NCH 16             // softmax stats chunks over l
#define KS 8               // gemm_out k-slabs

typedef __attribute__((ext_vector_type(8))) short s8v;           // 8 bf16 (4 VGPRs)
typedef __attribute__((ext_vector_type(4))) float f4v;           // 4 fp32
typedef __attribute__((ext_vector_type(4))) unsigned short u4v;  // 4 bf16 (8B)

struct f4u { float v[4]; };

__device__ __forceinline__ ushort f2bf(float f) {
    union { float f; unsigned u; } x; x.f = f;
    unsigned r = x.u + 0x7FFFu + ((x.u >> 16) & 1u);   // RNE
    return (ushort)(r >> 16);
}
__device__ __forceinline__ float bf2f(ushort u) {
    union { unsigned u; float f; } x; x.u = ((unsigned)u) << 16;
    return x.f;
}

// ---------- K1: per-position channel sums ----------
__global__ void prep_kernel(const float* __restrict__ fg, const float* __restrict__ mask,
                            float* __restrict__ Sfg, float* __restrict__ Sbg,
                            float* __restrict__ Qq) {
    int g = blockIdx.x * 256 + threadIdx.x;       // B*L threads
    int b = g >> 12, p = g & (LL - 1);
    float mval = mask[g];
    float s = 0.f, sb = 0.f, q = 0.f;
    const float* f = fg + (size_t)b * CC * LL + p;
    for (int c = 0; c < CC; ++c) {
        float v = f[(size_t)c * LL];
        s += v;
        float bv = v * (1.f - mval);
        sb += bv;
        q += bv * bv;
    }
    Sfg[g] = s; Sbg[g] = sb; Qq[g] = q;
}

// ---------- K2: inorm[l]=1/norm, winv[l]=norm, SfgTap[p]=valid-tap sum of Sfg ----------
__global__ void norm_kernel(const float* __restrict__ Sfg, const float* __restrict__ Sbg,
                            const float* __restrict__ Qq, float* __restrict__ inorm,
                            float* __restrict__ winv, float* __restrict__ SfgTap) {
    int g = blockIdx.x * 256 + threadIdx.x;       // B*L
    int b = g >> 12, l = g & (LL - 1);
    int i = l >> 6, j = l & 63;
    float n2 = 9.f * CC * EPSF * EPSF;
    float st = 0.f;
    for (int di = -1; di <= 1; ++di)
        for (int dj = -1; dj <= 1; ++dj) {
            int ii = i + di, jj = j + dj;
            if (ii >= 0 && ii < HH && jj >= 0 && jj < WW) {
                int idx = (b << 12) + (ii << 6) + jj;
                n2 += Qq[idx] + 2.f * EPSF * Sbg[idx];
                st += Sfg[idx];
            }
        }
    float n = sqrtf(n2);
    inorm[g] = 1.f / n;
    winv[g] = n;
    SfgTap[g] = st;
}

// ---------- K2b: per-sample bf16 copies: fgT/bgT [L][C] (transposed), bgH [C][L] ----------
__global__ __launch_bounds__(256) void transpose_kernel(const float* __restrict__ fgb,
                                                        const float* __restrict__ maskb,
                                                        ushort* __restrict__ fgT,
                                                        ushort* __restrict__ bgT,
                                                        ushort* __restrict__ bgH) {
    __shared__ float tile[64][65];
    int l0 = blockIdx.x * 64, c0 = blockIdx.y * 64;
    int tid = threadIdx.x, col = tid & 63, r0 = tid >> 6;
    for (int r = r0; r < 64; r += 4) {
        float v = fgb[(size_t)(c0 + r) * LL + l0 + col];
        tile[r][col] = v;
        bgH[(size_t)(c0 + r) * LL + l0 + col] = f2bf(v * (1.f - maskb[l0 + col]));
    }
    __syncthreads();
    for (int idx = tid; idx < 4096; idx += 256) {
        int row = idx >> 6;     // l offset
        int c = idx & 63;       // c offset
        float v = tile[c][row];
        size_t o = (size_t)(l0 + row) * CC + c0 + c;
        fgT[o] = f2bf(v);
        bgT[o] = f2bf(v * (1.f - maskb[l0 + row]));
    }
}

// ---------- K3: M = bg^T @ fg via MFMA bf16. A=bgT[L][C], B^T=fgT[L][C] ----------
__global__ __launch_bounds__(256) void gemm_M_mfma(const ushort* __restrict__ bgT,
                                                   const ushort* __restrict__ fgT,
                                                   float* __restrict__ M) {
    int lt = blockIdx.y, pt = blockIdx.x;            // 32x32 tiles of 128x128
    int wid = threadIdx.x >> 6, lane = threadIdx.x & 63;
    int wm = wid >> 1, wn = wid & 1;                 // 2x2 waves
    int lm = lane & 15, lk = lane >> 4;
    f4v acc[4][4] = {};
    int arow = lt * 128 + wm * 64 + lm;
    int brow = pt * 128 + wn * 64 + lm;
    for (int k0 = 0; k0 < CC; k0 += 32) {
        s8v a[4], bq[4];
        #pragma unroll
        for (int f = 0; f < 4; ++f)
            a[f] = *(const s8v*)(bgT + (size_t)(arow + f * 16) * CC + k0 + lk * 8);
        #pragma unroll
        for (int f = 0; f < 4; ++f)
            bq[f] = *(const s8v*)(fgT + (size_t)(brow + f * 16) * CC + k0 + lk * 8);
        #pragma unroll
        for (int mi = 0; mi < 4; ++mi)
            #pragma unroll
            for (int ni = 0; ni < 4; ++ni)
                acc[mi][ni] = __builtin_amdgcn_mfma_f32_16x16x32_bf16(a[mi], bq[ni], acc[mi][ni], 0, 0, 0);
    }
    #pragma unroll
    for (int mi = 0; mi < 4; ++mi)
        #pragma unroll
        for (int ni = 0; ni < 4; ++ni)
            #pragma unroll
            for (int r = 0; r < 4; ++r)
                M[(size_t)(lt * 128 + wm * 64 + mi * 16 + lk * 4 + r) * LL
                  + pt * 128 + wn * 64 + ni * 16 + lm] = acc[mi][ni][r];
}

// ---------- K4: REB[l,:] = exp( box_p((9-tap diag-sum of M + EPS*SfgTap)*inorm[l]) ) * inorm[l] ----------
__global__ __launch_bounds__(256) void scoresbox_kernel(const float* __restrict__ M,
                                                        const float* __restrict__ SfgTap,
                                                        const float* __restrict__ inorm,
                                                        float* __restrict__ REB, int bofs) {
    __shared__ float srow[LL + 136];
    float* sr = srow + 68;
    int l = blockIdx.x;
    int i = l >> 6, j = l & 63;
    float inl = inorm[bofs + l];
    for (int it = 0; it < 4; ++it) {
        int p = 4 * (threadIdx.x + it * 256);
        int y = p >> 6, x0 = p & 63;
        bool e0 = (x0 == 0), e3 = (x0 == 60);
        f4u t = *(const f4u*)(SfgTap + bofs + p);
        float s0 = EPSF * t.v[0], s1 = EPSF * t.v[1], s2 = EPSF * t.v[2], s3 = EPSF * t.v[3];
        #pragma unroll
        for (int di = -1; di <= 1; ++di) {
            int ii = i + di, yy = y + di;
            if ((unsigned)ii >= HH || (unsigned)yy >= HH) continue;
            #pragma unroll
            for (int dj = -1; dj <= 1; ++dj) {
                int jj = j + dj;
                if ((unsigned)jj >= WW) continue;
                int D = di * 64 + dj;
                f4u v = *(const f4u*)(M + (size_t)(l + D) * LL + (p + D));
                float v0 = v.v[0], v3 = v.v[3];
                if (dj == -1) v0 = e0 ? 0.f : v0;
                if (dj == 1)  v3 = e3 ? 0.f : v3;
                s0 += v0; s1 += v.v[1]; s2 += v.v[2]; s3 += v3;
            }
        }
        f4u o; o.v[0] = s0 * inl; o.v[1] = s1 * inl; o.v[2] = s2 * inl; o.v[3] = s3 * inl;
        *(f4u*)(sr + p) = o;
    }
    __syncthreads();
    for (int it = 0; it < 4; ++it) {
        int p = 4 * (threadIdx.x + it * 256);
        int y = p >> 6, x0 = p & 63;
        bool e0 = (x0 == 0), e3 = (x0 == 60);
        float b0 = 0.f, b1 = 0.f, b2 = 0.f, b3 = 0.f;
        #pragma unroll
        for (int gy = -1; gy <= 1; ++gy) {
            int yy = y + gy;
            if ((unsigned)yy >= HH) continue;
            int base = (yy << 6) + x0;
            float m1 = sr[base - 1], c0 = sr[base], c1 = sr[base + 1];
            float c2 = sr[base + 2], c3 = sr[base + 3], p4 = sr[base + 4];
            b0 += (e0 ? 0.f : m1) + c0 + c1;
            b1 += c0 + c1 + c2;
            b2 += c1 + c2 + c3;
            b3 += c2 + c3 + (e3 ? 0.f : p4);
        }
        // no-max-sub softmax numerator, row-scaled: REB = exp(SB)*inorm[l]
        f4u o;
        o.v[0] = __expf(b0) * inl; o.v[1] = __expf(b1) * inl;
        o.v[2] = __expf(b2) * inl; o.v[3] = __expf(b3) * inl;
        *(f4u*)(REB + (size_t)l * LL + p) = o;
    }
}

// ---------- K5: plain column sums: sumc=Σ REB*winv (=Σ exp), wsumc=Σ REB ----------
__global__ __launch_bounds__(256) void stats3_kernel(const float* __restrict__ REB,
                                                     const float* __restrict__ winv,
                                                     float* __restrict__ sumc,
                                                     float* __restrict__ wsumc, int bofs) {
    int pt = blockIdx.x, ch = blockIdx.y;
    int p = pt * 1024 + threadIdx.x * 4;
    float s0 = 0.f, s1 = 0.f, s2 = 0.f, s3 = 0.f;
    float w0 = 0.f, w1 = 0.f, w2 = 0.f, w3 = 0.f;
    int l0 = ch * (LL / NCH);
    for (int l = l0; l < l0 + LL / NCH; ++l) {
        f4u v = *(const f4u*)(REB + (size_t)l * LL + p);
        float wv = winv[bofs + l];
        w0 += v.v[0]; w1 += v.v[1]; w2 += v.v[2]; w3 += v.v[3];
        s0 += v.v[0] * wv; s1 += v.v[1] * wv; s2 += v.v[2] * wv; s3 += v.v[3] * wv;
    }
    int idx = ch * LL + p;
    f4u so; so.v[0] = s0; so.v[1] = s1; so.v[2] = s2; so.v[3] = s3;
    f4u wo; wo.v[0] = w0; wo.v[1] = w1; wo.v[2] = w2; wo.v[3] = w3;
    *(f4u*)(sumc + idx) = so;
    *(f4u*)(wsumc + idx) = wo;
}

// ---------- K5b: combine chunk sums: isum[p]=1/sumexp; Tp = box(wsum*isum) ----------
__global__ __launch_bounds__(192) void combine_ttap_kernel(const float* __restrict__ sumc,
                                                           const float* __restrict__ wsumc,
                                                           float* __restrict__ isum,
                                                           float* __restrict__ Tp) {
    __shared__ float bs[3][64];
    int yb = blockIdx.x;
    int t = threadIdx.x;              // 0..191
    int r = t >> 6, xcol = t & 63;    // r: row offset (yb-1+r)
    int yy = yb - 1 + r;
    float bv = 0.f;
    if ((unsigned)yy < HH) {
        int p = (yy << 6) + xcol;
        float se = 0.f, ws = 0.f;
        for (int ch = 0; ch < NCH; ++ch) {
            int idx = ch * LL + p;
            se += sumc[idx];
            ws += wsumc[idx];
        }
        float inv = 1.f / se;
        if (r == 1) isum[p] = inv;
        bv = ws * inv;
    }
    bs[r][xcol] = bv;
    __syncthreads();
    if (r == 1) {
        float tt = 0.f;
        #pragma unroll
        for (int rr = 0; rr < 3; ++rr) {
            tt += bs[rr][xcol];
            if (xcol > 0) tt += bs[rr][xcol - 1];
            if (xcol < 63) tt += bs[rr][xcol + 1];
        }
        Tp[(yb << 6) + xcol] = tt;
    }
}

// ---------- K7: fused 9-tap diag stencil + transpose: NnT[p][l] (bf16) ----------
// Valid taps never cross 64-boundaries -> operands are the 3 aligned 64x64
// REB blocks (i+di, y+di). Stage them (with isum folded) in LDS; 9 LDS
// reads/output; write NnT coalesced via LDS transpose tile.
__global__ __launch_bounds__(256) void ntile_kernel(const float* __restrict__ REB,
                                                    const float* __restrict__ isum,
                                                    ushort* __restrict__ NnT) {
    __shared__ float bandS[3][64][68];   // 52.2 KB
    __shared__ ushort T[64][68];         // 8.7 KB
    int i = blockIdx.x >> 6;   // l-block (spatial row of l)
    int y = blockIdx.x & 63;   // p-block (spatial row of p)
    int tid = threadIdx.x;

    // stage 3 diagonal bands, isum folded in
    #pragma unroll
    for (int di = -1; di <= 1; ++di) {
        int ii = i + di, yy = y + di;
        if ((unsigned)ii >= 64u || (unsigned)yy >= 64u) continue;
        const float* src = REB + ((size_t)ii * 64) * LL + yy * 64;
        const float* isrc = isum + yy * 64;
        int rp = tid >> 4, q = (tid & 15) * 4;
        #pragma unroll
        for (int pass = 0; pass < 4; ++pass) {
            int rr = pass * 16 + rp;
            f4u v = *(const f4u*)(src + (size_t)rr * LL + q);
            f4u w = *(const f4u*)(isrc + q);
            bandS[di + 1][rr][q + 0] = v.v[0] * w.v[0];
            bandS[di + 1][rr][q + 1] = v.v[1] * w.v[1];
            bandS[di + 1][rr][q + 2] = v.v[2] * w.v[2];
            bandS[di + 1][rr][q + 3] = v.v[3] * w.v[3];
        }
    }
    __syncthreads();

    // compute: thread = (x = tid&63, jb = tid>>6), 16 j's each
    int x = tid & 63, jb = tid >> 6;
    bool xm1 = (x >= 1), xp1 = (x <= 62);
    float accv[16];
    #pragma unroll
    for (int k = 0; k < 16; ++k) accv[k] = 0.f;
    #pragma unroll
    for (int di = -1; di <= 1; ++di) {
        int ii = i + di, yy = y + di;
        if ((unsigned)ii >= 64u || (unsigned)yy >= 64u) continue;
        const float (*B)[68] = bandS[di + 1];
        #pragma unroll
        for (int k = 0; k < 16; ++k) {
            int j = jb * 16 + k;
            float s = B[j][x];
            if (xm1 && j >= 1)  s += B[j - 1][x - 1];
            if (xp1 && j <= 62) s += B[j + 1][x + 1];
            accv[k] += s;
        }
    }
    #pragma unroll
    for (int k = 0; k < 16; ++k)
        T[x][jb * 16 + k] = f2bf(accv[k]);
    __syncthreads();

    // coalesced write: NnT row (y*64+xr), cols i*64 .. +63
    int xr = tid >> 2, q4 = tid & 3;
    size_t obase = (size_t)(y * 64 + xr) * LL + i * 64;
    #pragma unroll
    for (int k2 = 0; k2 < 2; ++k2) {
        int c0 = (k2 * 4 + q4) * 8;
        u4v v0 = *(const u4v*)&T[xr][c0];
        u4v v1 = *(const u4v*)&T[xr][c0 + 4];
        *(u4v*)(NnT + obase + c0) = v0;
        *(u4v*)(NnT + obase + c0 + 4) = v1;
    }
}

// ---------- K9a: partial rec = bgH @ NnT^T over a k-slab, MFMA ----------
__global__ __launch_bounds__(256) void gemm_out_part_mfma(const ushort* __restrict__ bgH,
                                                          const ushort* __restrict__ NnT,
                                                          float* __restrict__ part) {
    int pt = blockIdx.x, ks = blockIdx.y;
    int wid = threadIdx.x >> 6, lane = threadIdx.x & 63;
    int wm = wid >> 1, wn = wid & 1;
    int lm = lane & 15, lk = lane >> 4;
    f4v acc[4][2] = {};
    int arow = wm * 64 + lm;          // c
    int brow = pt * 64 + wn * 32 + lm; // p
    int kbeg = ks * (LL / KS);
    #pragma unroll 2
    for (int k0 = kbeg; k0 < kbeg + LL / KS; k0 += 32) {
        s8v a[4], bq[2];
        #pragma unroll
        for (int f = 0; f < 4; ++f)
            a[f] = *(const s8v*)(bgH + (size_t)(arow + f * 16) * LL + k0 + lk * 8);
        #pragma unroll
        for (int f = 0; f < 2; ++f)
            bq[f] = *(const s8v*)(NnT + (size_t)(brow + f * 16) * LL + k0 + lk * 8);
        #pragma unroll
        for (int mi = 0; mi < 4; ++mi)
            #pragma unroll
            for (int ni = 0; ni < 2; ++ni)
                acc[mi][ni] = __builtin_amdgcn_mfma_f32_16x16x32_bf16(a[mi], bq[ni], acc[mi][ni], 0, 0, 0);
    }
    #pragma unroll
    for (int mi = 0; mi < 4; ++mi)
        #pragma unroll
        for (int ni = 0; ni < 2; ++ni)
            #pragma unroll
            for (int r = 0; r < 4; ++r)
                part[((size_t)ks * CC + wm * 64 + mi * 16 + lk * 4 + r) * LL
                     + pt * 64 + wn * 32 + ni * 16 + lm] = acc[mi][ni][r];
}

// ---------- K9b: combine slabs + epilogue ----------
__global__ void epilogue_kernel(const float* __restrict__ part, const float* __restrict__ Tp,
                                const float* __restrict__ fgb, const float* __restrict__ maskb,
                                float* __restrict__ outb) {
    int g = blockIdx.x * 256 + threadIdx.x;   // C*L
    int p = g & 4095;
    float acc = 0.f;
    for (int ks = 0; ks < KS; ++ks)
        acc += part[(size_t)ks * CC * LL + g];
    float rec = acc + EPSF * Tp[p];
    float mval = maskb[p];
    outb[g] = rec * mval * (1.f / 9.f) + fgb[g] * (1.f - mval);
}

extern "C" void kernel_launch(void* const* d_in, const int* in_sizes, int n_in,
                              void* d_out, int out_size, void* d_ws, size_t ws_size,
                              hipStream_t stream) {
    const float* fg = (const float*)d_in[0];     // [B,C,H,W]
    const float* mask = (const float*)d_in[1];   // [B,1,H,W]
    float* out = (float*)d_out;
    float* ws = (float*)d_ws;

    // ws layout (~133 MiB, proven size)
    float* Sfg = ws;                                 // B*LL each:
    float* Sbg = Sfg + BB * LL;
    float* Qq = Sbg + BB * LL;
    float* inorm = Qq + BB * LL;
    float* winv = inorm + BB * LL;
    float* SfgTap = winv + BB * LL;
    float* sumc = SfgTap + BB * LL;                  // NCH*LL each:
    float* wsumc = sumc + NCH * LL;
    float* isum = wsumc + NCH * LL;                  // LL each:
    float* Tp = isum + LL;
    ushort* bgH = (ushort*)(Tp + LL);                // B*CC*LL ushorts (4 MiB)
    float* bufA = (float*)(bgH + (size_t)BB * CC * LL);   // LL2 (M, then NnT)
    float* bufB = bufA + LL2;                        // LL2 (REB, then part)
    // per-sample transposed bf16 operand tiles live in bufB tail (dead until scoresbox):
    ushort* bgT = (ushort*)(bufB + 8 * 1024 * 1024);
    ushort* fgT = bgT + (size_t)LL * CC;
    // after scoresbox, M (bufA) is dead -> reuse for NnT (32 MB):
    ushort* NnT = (ushort*)bufA;
    // after ntile, REB (bufB) is dead -> reuse for fp32 partials (16 MB):
    float* part = bufB;

    prep_kernel<<<BB * LL / 256, 256, 0, stream>>>(fg, mask, Sfg, Sbg, Qq);
    norm_kernel<<<BB * LL / 256, 256, 0, stream>>>(Sfg, Sbg, Qq, inorm, winv, SfgTap);

    for (int b = 0; b < BB; ++b) {
        const float* fgb = fg + (size_t)b * CC * LL;
        const float* mb = mask + (size_t)b * LL;
        ushort* bgHb = bgH + (size_t)b * CC * LL;
        int bofs = b * LL;

        transpose_kernel<<<dim3(64, 2), 256, 0, stream>>>(fgb, mb, fgT, bgT, bgHb);
        gemm_M_mfma<<<dim3(32, 32), 256, 0, stream>>>(bgT, fgT, bufA);
        scoresbox_kernel<<<LL, 256, 0, stream>>>(bufA, SfgTap, inorm, bufB, bofs);
        stats3_kernel<<<dim3(4, NCH), 256, 0, stream>>>(bufB, winv, sumc, wsumc, bofs);
        combine_ttap_kernel<<<64, 192, 0, stream>>>(sumc, wsumc, isum, Tp);
        ntile_kernel<<<4096, 256, 0, stream>>>(bufB, isum, NnT);
        gemm_out_part_mfma<<<dim3(64, KS), 256, 0, stream>>>(bgHb, NnT, part);
        epilogue_kernel<<<CC * LL / 256, 256, 0, stream>>>(part, Tp, fgb, mb, out + (size_t)b * CC * LL);
    }
}

// Round 8
// 833.058 us; speedup vs baseline: 1.3373x; 1.0120x over previous
//
#include <hip/hip_runtime.h>
#include <math.h>

#define BB 4
#define CC 128
#define HH 64
#define WW 64
#define LL 4096            // H*W
#define LL2 ((size_t)LL*LL)
#define EPSF 1e-7f
#define NCH 16             // softmax stats chunks over l
#define KS 8               // gemm_out k-slabs

typedef __attribute__((ext_vector_type(8))) short s8v;           // 8 bf16 (4 VGPRs)
typedef __attribute__((ext_vector_type(4))) float f4v;           // 4 fp32
typedef __attribute__((ext_vector_type(4))) unsigned short u4v;  // 4 bf16 (8B)

struct f4u { float v[4]; };

__device__ __forceinline__ ushort f2bf(float f) {
    union { float f; unsigned u; } x; x.f = f;
    unsigned r = x.u + 0x7FFFu + ((x.u >> 16) & 1u);   // RNE
    return (ushort)(r >> 16);
}
__device__ __forceinline__ float bf2f(ushort u) {
    union { unsigned u; float f; } x; x.u = ((unsigned)u) << 16;
    return x.f;
}

// ---------- K1: per-position channel sums ----------
__global__ void prep_kernel(const float* __restrict__ fg, const float* __restrict__ mask,
                            float* __restrict__ Sfg, float* __restrict__ Sbg,
                            float* __restrict__ Qq) {
    int g = blockIdx.x * 256 + threadIdx.x;       // B*L threads
    int b = g >> 12, p = g & (LL - 1);
    float mval = mask[g];
    float s = 0.f, sb = 0.f, q = 0.f;
    const float* f = fg + (size_t)b * CC * LL + p;
    for (int c = 0; c < CC; ++c) {
        float v = f[(size_t)c * LL];
        s += v;
        float bv = v * (1.f - mval);
        sb += bv;
        q += bv * bv;
    }
    Sfg[g] = s; Sbg[g] = sb; Qq[g] = q;
}

// ---------- K2: inorm[l]=1/norm, winv[l]=norm, SfgTap[p]=valid-tap sum of Sfg ----------
__global__ void norm_kernel(const float* __restrict__ Sfg, const float* __restrict__ Sbg,
                            const float* __restrict__ Qq, float* __restrict__ inorm,
                            float* __restrict__ winv, float* __restrict__ SfgTap) {
    int g = blockIdx.x * 256 + threadIdx.x;       // B*L
    int b = g >> 12, l = g & (LL - 1);
    int i = l >> 6, j = l & 63;
    float n2 = 9.f * CC * EPSF * EPSF;
    float st = 0.f;
    for (int di = -1; di <= 1; ++di)
        for (int dj = -1; dj <= 1; ++dj) {
            int ii = i + di, jj = j + dj;
            if (ii >= 0 && ii < HH && jj >= 0 && jj < WW) {
                int idx = (b << 12) + (ii << 6) + jj;
                n2 += Qq[idx] + 2.f * EPSF * Sbg[idx];
                st += Sfg[idx];
            }
        }
    float n = sqrtf(n2);
    inorm[g] = 1.f / n;
    winv[g] = n;
    SfgTap[g] = st;
}

// ---------- K2b: per-sample bf16 copies: fgT/bgT [L][C] (transposed), bgH [C][L] ----------
__global__ __launch_bounds__(256) void transpose_kernel(const float* __restrict__ fgb,
                                                        const float* __restrict__ maskb,
                                                        ushort* __restrict__ fgT,
                                                        ushort* __restrict__ bgT,
                                                        ushort* __restrict__ bgH) {
    __shared__ float tile[64][65];
    int l0 = blockIdx.x * 64, c0 = blockIdx.y * 64;
    int tid = threadIdx.x, col = tid & 63, r0 = tid >> 6;
    for (int r = r0; r < 64; r += 4) {
        float v = fgb[(size_t)(c0 + r) * LL + l0 + col];
        tile[r][col] = v;
        bgH[(size_t)(c0 + r) * LL + l0 + col] = f2bf(v * (1.f - maskb[l0 + col]));
    }
    __syncthreads();
    for (int idx = tid; idx < 4096; idx += 256) {
        int row = idx >> 6;     // l offset
        int c = idx & 63;       // c offset
        float v = tile[c][row];
        size_t o = (size_t)(l0 + row) * CC + c0 + c;
        fgT[o] = f2bf(v);
        bgT[o] = f2bf(v * (1.f - maskb[l0 + row]));
    }
}

// ---------- K3: M = bg^T @ fg via MFMA bf16. A=bgT[L][C], B^T=fgT[L][C] ----------
__global__ __launch_bounds__(256) void gemm_M_mfma(const ushort* __restrict__ bgT,
                                                   const ushort* __restrict__ fgT,
                                                   float* __restrict__ M) {
    int lt = blockIdx.y, pt = blockIdx.x;            // 32x32 tiles of 128x128
    int wid = threadIdx.x >> 6, lane = threadIdx.x & 63;
    int wm = wid >> 1, wn = wid & 1;                 // 2x2 waves
    int lm = lane & 15, lk = lane >> 4;
    f4v acc[4][4] = {};
    int arow = lt * 128 + wm * 64 + lm;
    int brow = pt * 128 + wn * 64 + lm;
    for (int k0 = 0; k0 < CC; k0 += 32) {
        s8v a[4], bq[4];
        #pragma unroll
        for (int f = 0; f < 4; ++f)
            a[f] = *(const s8v*)(bgT + (size_t)(arow + f * 16) * CC + k0 + lk * 8);
        #pragma unroll
        for (int f = 0; f < 4; ++f)
            bq[f] = *(const s8v*)(fgT + (size_t)(brow + f * 16) * CC + k0 + lk * 8);
        #pragma unroll
        for (int mi = 0; mi < 4; ++mi)
            #pragma unroll
            for (int ni = 0; ni < 4; ++ni)
                acc[mi][ni] = __builtin_amdgcn_mfma_f32_16x16x32_bf16(a[mi], bq[ni], acc[mi][ni], 0, 0, 0);
    }
    #pragma unroll
    for (int mi = 0; mi < 4; ++mi)
        #pragma unroll
        for (int ni = 0; ni < 4; ++ni)
            #pragma unroll
            for (int r = 0; r < 4; ++r)
                M[(size_t)(lt * 128 + wm * 64 + mi * 16 + lk * 4 + r) * LL
                  + pt * 128 + wn * 64 + ni * 16 + lm] = acc[mi][ni][r];
}

// ---------- K4: REB[l,:] (bf16) = exp( box_p((9-tap diag-sum of M + EPS*SfgTap)*inorm[l]) ) * inorm[l] ----------
__global__ __launch_bounds__(256) void scoresbox_kernel(const float* __restrict__ M,
                                                        const float* __restrict__ SfgTap,
                                                        const float* __restrict__ inorm,
                                                        ushort* __restrict__ REB, int bofs) {
    __shared__ float srow[LL + 136];
    float* sr = srow + 68;
    int l = blockIdx.x;
    int i = l >> 6, j = l & 63;
    float inl = inorm[bofs + l];
    for (int it = 0; it < 4; ++it) {
        int p = 4 * (threadIdx.x + it * 256);
        int y = p >> 6, x0 = p & 63;
        bool e0 = (x0 == 0), e3 = (x0 == 60);
        f4u t = *(const f4u*)(SfgTap + bofs + p);
        float s0 = EPSF * t.v[0], s1 = EPSF * t.v[1], s2 = EPSF * t.v[2], s3 = EPSF * t.v[3];
        #pragma unroll
        for (int di = -1; di <= 1; ++di) {
            int ii = i + di, yy = y + di;
            if ((unsigned)ii >= HH || (unsigned)yy >= HH) continue;
            #pragma unroll
            for (int dj = -1; dj <= 1; ++dj) {
                int jj = j + dj;
                if ((unsigned)jj >= WW) continue;
                int D = di * 64 + dj;
                f4u v = *(const f4u*)(M + (size_t)(l + D) * LL + (p + D));
                float v0 = v.v[0], v3 = v.v[3];
                if (dj == -1) v0 = e0 ? 0.f : v0;
                if (dj == 1)  v3 = e3 ? 0.f : v3;
                s0 += v0; s1 += v.v[1]; s2 += v.v[2]; s3 += v3;
            }
        }
        f4u o; o.v[0] = s0 * inl; o.v[1] = s1 * inl; o.v[2] = s2 * inl; o.v[3] = s3 * inl;
        *(f4u*)(sr + p) = o;
    }
    __syncthreads();
    for (int it = 0; it < 4; ++it) {
        int p = 4 * (threadIdx.x + it * 256);
        int y = p >> 6, x0 = p & 63;
        bool e0 = (x0 == 0), e3 = (x0 == 60);
        float b0 = 0.f, b1 = 0.f, b2 = 0.f, b3 = 0.f;
        #pragma unroll
        for (int gy = -1; gy <= 1; ++gy) {
            int yy = y + gy;
            if ((unsigned)yy >= HH) continue;
            int base = (yy << 6) + x0;
            float m1 = sr[base - 1], c0 = sr[base], c1 = sr[base + 1];
            float c2 = sr[base + 2], c3 = sr[base + 3], p4 = sr[base + 4];
            b0 += (e0 ? 0.f : m1) + c0 + c1;
            b1 += c0 + c1 + c2;
            b2 += c1 + c2 + c3;
            b3 += c2 + c3 + (e3 ? 0.f : p4);
        }
        // no-max-sub softmax numerator, row-scaled, quantized to bf16
        u4v o;
        o[0] = f2bf(__expf(b0) * inl); o[1] = f2bf(__expf(b1) * inl);
        o[2] = f2bf(__expf(b2) * inl); o[3] = f2bf(__expf(b3) * inl);
        *(u4v*)(REB + (size_t)l * LL + p) = o;
    }
}

// ---------- K5: plain column sums over bf16 REB: sumc=Σ REB*winv, wsumc=Σ REB ----------
__global__ __launch_bounds__(256) void stats3_kernel(const ushort* __restrict__ REB,
                                                     const float* __restrict__ winv,
                                                     float* __restrict__ sumc,
                                                     float* __restrict__ wsumc, int bofs) {
    int pt = blockIdx.x, ch = blockIdx.y;
    int p = pt * 2048 + threadIdx.x * 8;
    float s[8] = {}, w[8] = {};
    int l0 = ch * (LL / NCH);
    for (int l = l0; l < l0 + LL / NCH; ++l) {
        u4v h0 = *(const u4v*)(REB + (size_t)l * LL + p);
        u4v h1 = *(const u4v*)(REB + (size_t)l * LL + p + 4);
        float wv = winv[bofs + l];
        float v0 = bf2f(h0[0]), v1 = bf2f(h0[1]), v2 = bf2f(h0[2]), v3 = bf2f(h0[3]);
        float v4 = bf2f(h1[0]), v5 = bf2f(h1[1]), v6 = bf2f(h1[2]), v7 = bf2f(h1[3]);
        w[0] += v0; w[1] += v1; w[2] += v2; w[3] += v3;
        w[4] += v4; w[5] += v5; w[6] += v6; w[7] += v7;
        s[0] += v0 * wv; s[1] += v1 * wv; s[2] += v2 * wv; s[3] += v3 * wv;
        s[4] += v4 * wv; s[5] += v5 * wv; s[6] += v6 * wv; s[7] += v7 * wv;
    }
    int idx = ch * LL + p;
    #pragma unroll
    for (int h = 0; h < 2; ++h) {
        f4u so, wo;
        #pragma unroll
        for (int k = 0; k < 4; ++k) { so.v[k] = s[h * 4 + k]; wo.v[k] = w[h * 4 + k]; }
        *(f4u*)(sumc + idx + h * 4) = so;
        *(f4u*)(wsumc + idx + h * 4) = wo;
    }
}

// ---------- K5b: combine chunk sums: isum[p]=1/sumexp; Tp = box(wsum*isum) ----------
__global__ __launch_bounds__(192) void combine_ttap_kernel(const float* __restrict__ sumc,
                                                           const float* __restrict__ wsumc,
                                                           float* __restrict__ isum,
                                                           float* __restrict__ Tp) {
    __shared__ float bs[3][64];
    int yb = blockIdx.x;
    int t = threadIdx.x;              // 0..191
    int r = t >> 6, xcol = t & 63;    // r: row offset (yb-1+r)
    int yy = yb - 1 + r;
    float bv = 0.f;
    if ((unsigned)yy < HH) {
        int p = (yy << 6) + xcol;
        float se = 0.f, ws = 0.f;
        for (int ch = 0; ch < NCH; ++ch) {
            int idx = ch * LL + p;
            se += sumc[idx];
            ws += wsumc[idx];
        }
        float inv = 1.f / se;
        if (r == 1) isum[p] = inv;
        bv = ws * inv;
    }
    bs[r][xcol] = bv;
    __syncthreads();
    if (r == 1) {
        float tt = 0.f;
        #pragma unroll
        for (int rr = 0; rr < 3; ++rr) {
            tt += bs[rr][xcol];
            if (xcol > 0) tt += bs[rr][xcol - 1];
            if (xcol < 63) tt += bs[rr][xcol + 1];
        }
        Tp[(yb << 6) + xcol] = tt;
    }
}

// ---------- K7 v2: fused 9-tap diag stencil + transpose, j-split for occupancy ----------
// block = (i, y, jhalf): 32(j) x 64(x) output subtile of NnT.
// LDS: 3 bands x rows [j0-1, j0+32] x 64 cols (fp32, isum folded) ~27.7KB + T ~4.5KB.
__global__ __launch_bounds__(256) void ntile_kernel(const ushort* __restrict__ REB,
                                                    const float* __restrict__ isum,
                                                    ushort* __restrict__ NnT) {
    __shared__ float bandS[3][34][68];   // 27.7 KB
    __shared__ ushort T[64][36];         // 4.5 KB
    int bid = blockIdx.x;
    int jh = bid & 1;            // j-half
    int y = (bid >> 1) & 63;     // p spatial row
    int i = bid >> 7;            // l spatial row
    int j0 = jh * 32;
    int tid = threadIdx.x;

    // stage 3 diagonal bands (global j rows j0-1 .. j0+32), isum folded in
    #pragma unroll
    for (int di = -1; di <= 1; ++di) {
        int ii = i + di, yy = y + di;
        float* dstB = &bandS[di + 1][0][0];
        if ((unsigned)ii >= 64u || (unsigned)yy >= 64u) {
            for (int idx = tid; idx < 34 * 68; idx += 256) dstB[idx] = 0.f;
            continue;
        }
        const ushort* src = REB + ((size_t)ii * 64) * LL + yy * 64;
        const float* isrc = isum + yy * 64;
        for (int idx = tid; idx < 34 * 8; idx += 256) {
            int r = idx >> 3, cg = (idx & 7) * 8;
            int jg = j0 - 1 + r;            // global j row
            float* dst = &bandS[di + 1][r][cg];
            if ((unsigned)jg < 64u) {
                u4v h0 = *(const u4v*)(src + (size_t)jg * LL + cg);
                u4v h1 = *(const u4v*)(src + (size_t)jg * LL + cg + 4);
                f4u w0 = *(const f4u*)(isrc + cg);
                f4u w1 = *(const f4u*)(isrc + cg + 4);
                dst[0] = bf2f(h0[0]) * w0.v[0];
                dst[1] = bf2f(h0[1]) * w0.v[1];
                dst[2] = bf2f(h0[2]) * w0.v[2];
                dst[3] = bf2f(h0[3]) * w0.v[3];
                dst[4] = bf2f(h1[0]) * w1.v[0];
                dst[5] = bf2f(h1[1]) * w1.v[1];
                dst[6] = bf2f(h1[2]) * w1.v[2];
                dst[7] = bf2f(h1[3]) * w1.v[3];
            } else {
                #pragma unroll
                for (int k = 0; k < 8; ++k) dst[k] = 0.f;
            }
        }
    }
    __syncthreads();

    // compute: thread = (x = tid&63, jb = tid>>6), 8 j's each
    int x = tid & 63, jb = tid >> 6;
    bool xm1 = (x >= 1), xp1 = (x <= 62);
    float accv[8];
    #pragma unroll
    for (int k = 0; k < 8; ++k) accv[k] = 0.f;
    #pragma unroll
    for (int d3 = 0; d3 < 3; ++d3) {
        const float (*B)[68] = bandS[d3];
        #pragma unroll
        for (int k = 0; k < 8; ++k) {
            int jl = jb * 8 + k;       // 0..31
            int j = j0 + jl;           // global j
            int rc = jl + 1;           // band row of center tap
            float s = B[rc][x];
            if (xm1 && j >= 1)  s += B[rc - 1][x - 1];
            if (xp1 && j <= 62) s += B[rc + 1][x + 1];
            accv[k] += s;
        }
    }
    #pragma unroll
    for (int k = 0; k < 8; ++k)
        T[x][jb * 8 + k] = f2bf(accv[k]);
    __syncthreads();

    // coalesced write: NnT row (y*64+xr), cols i*64 + j0 + [0,32)
    int xr = tid >> 2, q4 = tid & 3;
    size_t obase = (size_t)(y * 64 + xr) * LL + i * 64 + j0 + q4 * 8;
    u4v v0 = *(const u4v*)&T[xr][q4 * 8];
    u4v v1 = *(const u4v*)&T[xr][q4 * 8 + 4];
    *(u4v*)(NnT + obase) = v0;
    *(u4v*)(NnT + obase + 4) = v1;
}

// ---------- K9a: partial rec = bgH @ NnT^T over a k-slab, MFMA ----------
__global__ __launch_bounds__(256) void gemm_out_part_mfma(const ushort* __restrict__ bgH,
                                                          const ushort* __restrict__ NnT,
                                                          float* __restrict__ part) {
    int pt = blockIdx.x, ks = blockIdx.y;
    int wid = threadIdx.x >> 6, lane = threadIdx.x & 63;
    int wm = wid >> 1, wn = wid & 1;
    int lm = lane & 15, lk = lane >> 4;
    f4v acc[4][2] = {};
    int arow = wm * 64 + lm;          // c
    int brow = pt * 64 + wn * 32 + lm; // p
    int kbeg = ks * (LL / KS);
    #pragma unroll 2
    for (int k0 = kbeg; k0 < kbeg + LL / KS; k0 += 32) {
        s8v a[4], bq[2];
        #pragma unroll
        for (int f = 0; f < 4; ++f)
            a[f] = *(const s8v*)(bgH + (size_t)(arow + f * 16) * LL + k0 + lk * 8);
        #pragma unroll
        for (int f = 0; f < 2; ++f)
            bq[f] = *(const s8v*)(NnT + (size_t)(brow + f * 16) * LL + k0 + lk * 8);
        #pragma unroll
        for (int mi = 0; mi < 4; ++mi)
            #pragma unroll
            for (int ni = 0; ni < 2; ++ni)
                acc[mi][ni] = __builtin_amdgcn_mfma_f32_16x16x32_bf16(a[mi], bq[ni], acc[mi][ni], 0, 0, 0);
    }
    #pragma unroll
    for (int mi = 0; mi < 4; ++mi)
        #pragma unroll
        for (int ni = 0; ni < 2; ++ni)
            #pragma unroll
            for (int r = 0; r < 4; ++r)
                part[((size_t)ks * CC + wm * 64 + mi * 16 + lk * 4 + r) * LL
                     + pt * 64 + wn * 32 + ni * 16 + lm] = acc[mi][ni][r];
}

// ---------- K9b: combine slabs + epilogue ----------
__global__ void epilogue_kernel(const float* __restrict__ part, const float* __restrict__ Tp,
                                const float* __restrict__ fgb, const float* __restrict__ maskb,
                                float* __restrict__ outb) {
    int g = blockIdx.x * 256 + threadIdx.x;   // C*L
    int p = g & 4095;
    float acc = 0.f;
    for (int ks = 0; ks < KS; ++ks)
        acc += part[(size_t)ks * CC * LL + g];
    float rec = acc + EPSF * Tp[p];
    float mval = maskb[p];
    outb[g] = rec * mval * (1.f / 9.f) + fgb[g] * (1.f - mval);
}

extern "C" void kernel_launch(void* const* d_in, const int* in_sizes, int n_in,
                              void* d_out, int out_size, void* d_ws, size_t ws_size,
                              hipStream_t stream) {
    const float* fg = (const float*)d_in[0];     // [B,C,H,W]
    const float* mask = (const float*)d_in[1];   // [B,1,H,W]
    float* out = (float*)d_out;
    float* ws = (float*)d_ws;

    // ws layout (~133 MiB, proven size)
    float* Sfg = ws;                                 // B*LL each:
    float* Sbg = Sfg + BB * LL;
    float* Qq = Sbg + BB * LL;
    float* inorm = Qq + BB * LL;
    float* winv = inorm + BB * LL;
    float* SfgTap = winv + BB * LL;
    float* sumc = SfgTap + BB * LL;                  // NCH*LL each:
    float* wsumc = sumc + NCH * LL;
    float* isum = wsumc + NCH * LL;                  // LL each:
    float* Tp = isum + LL;
    ushort* bgH = (ushort*)(Tp + LL);                // B*CC*LL ushorts (4 MiB)
    float* bufA = (float*)(bgH + (size_t)BB * CC * LL);   // LL2 (M, then NnT)
    float* bufB = bufA + LL2;                        // LL2 (REB16 in first half, then part)
    // per-sample transposed bf16 operand tiles live in bufB tail (dead until scoresbox):
    ushort* bgT = (ushort*)(bufB + 8 * 1024 * 1024);
    ushort* fgT = bgT + (size_t)LL * CC;
    // REB bf16 occupies first 32 MB of bufB:
    ushort* REB16 = (ushort*)bufB;
    // after scoresbox, M (bufA) is dead -> reuse for NnT (32 MB):
    ushort* NnT = (ushort*)bufA;
    // after ntile, REB16 (bufB) is dead -> reuse for fp32 partials (16 MB):
    float* part = bufB;

    prep_kernel<<<BB * LL / 256, 256, 0, stream>>>(fg, mask, Sfg, Sbg, Qq);
    norm_kernel<<<BB * LL / 256, 256, 0, stream>>>(Sfg, Sbg, Qq, inorm, winv, SfgTap);

    for (int b = 0; b < BB; ++b) {
        const float* fgb = fg + (size_t)b * CC * LL;
        const float* mb = mask + (size_t)b * LL;
        ushort* bgHb = bgH + (size_t)b * CC * LL;
        int bofs = b * LL;

        transpose_kernel<<<dim3(64, 2), 256, 0, stream>>>(fgb, mb, fgT, bgT, bgHb);
        gemm_M_mfma<<<dim3(32, 32), 256, 0, stream>>>(bgT, fgT, bufA);
        scoresbox_kernel<<<LL, 256, 0, stream>>>(bufA, SfgTap, inorm, REB16, bofs);
        stats3_kernel<<<dim3(2, NCH), 256, 0, stream>>>(REB16, winv, sumc, wsumc, bofs);
        combine_ttap_kernel<<<64, 192, 0, stream>>>(sumc, wsumc, isum, Tp);
        ntile_kernel<<<8192, 256, 0, stream>>>(REB16, isum, NnT);
        gemm_out_part_mfma<<<dim3(64, KS), 256, 0, stream>>>(bgHb, NnT, part);
        epilogue_kernel<<<CC * LL / 256, 256, 0, stream>>>(part, Tp, fgb, mb, out + (size_t)b * CC * LL);
    }
}

// Round 9
// 682.575 us; speedup vs baseline: 1.6321x; 1.2205x over previous
//
#include <hip/hip_runtime.h>
#include <math.h>

#define BB 4
#define CC 128
#define HH 64
#define WW 64
#define LL 4096            // H*W
#define LL2 ((size_t)LL*LL)
#define EPSF 1e-7f
#define NCH 64             // softmax stats chunks over l
#define KS 8               // gemm_out k-slabs

typedef __attribute__((ext_vector_type(8))) short s8v;           // 8 bf16 (4 VGPRs)
typedef __attribute__((ext_vector_type(4))) float f4v;           // 4 fp32
typedef __attribute__((ext_vector_type(4))) unsigned short u4v;  // 4 bf16 (8B)

struct f4u { float v[4]; };

__device__ __forceinline__ ushort f2bf(float f) {
    union { float f; unsigned u; } x; x.f = f;
    unsigned r = x.u + 0x7FFFu + ((x.u >> 16) & 1u);   // RNE
    return (ushort)(r >> 16);
}
__device__ __forceinline__ float bf2f(ushort u) {
    union { unsigned u; float f; } x; x.u = ((unsigned)u) << 16;
    return x.f;
}

// ---------- K1: per-position channel sums ----------
__global__ void prep_kernel(const float* __restrict__ fg, const float* __restrict__ mask,
                            float* __restrict__ Sfg, float* __restrict__ Sbg,
                            float* __restrict__ Qq) {
    int g = blockIdx.x * 256 + threadIdx.x;       // B*L threads
    int b = g >> 12, p = g & (LL - 1);
    float mval = mask[g];
    float s = 0.f, sb = 0.f, q = 0.f;
    const float* f = fg + (size_t)b * CC * LL + p;
    for (int c = 0; c < CC; ++c) {
        float v = f[(size_t)c * LL];
        s += v;
        float bv = v * (1.f - mval);
        sb += bv;
        q += bv * bv;
    }
    Sfg[g] = s; Sbg[g] = sb; Qq[g] = q;
}

// ---------- K2: inorm[l]=1/norm, winv[l]=norm, SfgTap[p]=valid-tap sum of Sfg ----------
__global__ void norm_kernel(const float* __restrict__ Sfg, const float* __restrict__ Sbg,
                            const float* __restrict__ Qq, float* __restrict__ inorm,
                            float* __restrict__ winv, float* __restrict__ SfgTap) {
    int g = blockIdx.x * 256 + threadIdx.x;       // B*L
    int b = g >> 12, l = g & (LL - 1);
    int i = l >> 6, j = l & 63;
    float n2 = 9.f * CC * EPSF * EPSF;
    float st = 0.f;
    for (int di = -1; di <= 1; ++di)
        for (int dj = -1; dj <= 1; ++dj) {
            int ii = i + di, jj = j + dj;
            if (ii >= 0 && ii < HH && jj >= 0 && jj < WW) {
                int idx = (b << 12) + (ii << 6) + jj;
                n2 += Qq[idx] + 2.f * EPSF * Sbg[idx];
                st += Sfg[idx];
            }
        }
    float n = sqrtf(n2);
    inorm[g] = 1.f / n;
    winv[g] = n;
    SfgTap[g] = st;
}

// ---------- K2b: per-sample bf16 copies: fgT/bgT [L][C] (transposed), bgH [C][L] ----------
__global__ __launch_bounds__(256) void transpose_kernel(const float* __restrict__ fgb,
                                                        const float* __restrict__ maskb,
                                                        ushort* __restrict__ fgT,
                                                        ushort* __restrict__ bgT,
                                                        ushort* __restrict__ bgH) {
    __shared__ float tile[64][65];
    int l0 = blockIdx.x * 64, c0 = blockIdx.y * 64;
    int tid = threadIdx.x, col = tid & 63, r0 = tid >> 6;
    for (int r = r0; r < 64; r += 4) {
        float v = fgb[(size_t)(c0 + r) * LL + l0 + col];
        tile[r][col] = v;
        bgH[(size_t)(c0 + r) * LL + l0 + col] = f2bf(v * (1.f - maskb[l0 + col]));
    }
    __syncthreads();
    for (int idx = tid; idx < 4096; idx += 256) {
        int row = idx >> 6;     // l offset
        int c = idx & 63;       // c offset
        float v = tile[c][row];
        size_t o = (size_t)(l0 + row) * CC + c0 + c;
        fgT[o] = f2bf(v);
        bgT[o] = f2bf(v * (1.f - maskb[l0 + row]));
    }
}

// ---------- K3: M = bg^T @ fg via MFMA bf16. A=bgT[L][C], B^T=fgT[L][C] ----------
__global__ __launch_bounds__(256) void gemm_M_mfma(const ushort* __restrict__ bgT,
                                                   const ushort* __restrict__ fgT,
                                                   float* __restrict__ M) {
    int lt = blockIdx.y, pt = blockIdx.x;            // 32x32 tiles of 128x128
    int wid = threadIdx.x >> 6, lane = threadIdx.x & 63;
    int wm = wid >> 1, wn = wid & 1;                 // 2x2 waves
    int lm = lane & 15, lk = lane >> 4;
    f4v acc[4][4] = {};
    int arow = lt * 128 + wm * 64 + lm;
    int brow = pt * 128 + wn * 64 + lm;
    for (int k0 = 0; k0 < CC; k0 += 32) {
        s8v a[4], bq[4];
        #pragma unroll
        for (int f = 0; f < 4; ++f)
            a[f] = *(const s8v*)(bgT + (size_t)(arow + f * 16) * CC + k0 + lk * 8);
        #pragma unroll
        for (int f = 0; f < 4; ++f)
            bq[f] = *(const s8v*)(fgT + (size_t)(brow + f * 16) * CC + k0 + lk * 8);
        #pragma unroll
        for (int mi = 0; mi < 4; ++mi)
            #pragma unroll
            for (int ni = 0; ni < 4; ++ni)
                acc[mi][ni] = __builtin_amdgcn_mfma_f32_16x16x32_bf16(a[mi], bq[ni], acc[mi][ni], 0, 0, 0);
    }
    #pragma unroll
    for (int mi = 0; mi < 4; ++mi)
        #pragma unroll
        for (int ni = 0; ni < 4; ++ni)
            #pragma unroll
            for (int r = 0; r < 4; ++r)
                M[(size_t)(lt * 128 + wm * 64 + mi * 16 + lk * 4 + r) * LL
                  + pt * 128 + wn * 64 + ni * 16 + lm] = acc[mi][ni][r];
}

// ---------- K4: REB[l,:] (bf16) = exp( box_p((9-tap diag-sum of M + EPS*SfgTap)*inorm[l]) ) * inorm[l] ----------
__global__ __launch_bounds__(256) void scoresbox_kernel(const float* __restrict__ M,
                                                        const float* __restrict__ SfgTap,
                                                        const float* __restrict__ inorm,
                                                        ushort* __restrict__ REB, int bofs) {
    __shared__ float srow[LL + 136];
    float* sr = srow + 68;
    int l = blockIdx.x;
    int i = l >> 6, j = l & 63;
    float inl = inorm[bofs + l];
    for (int it = 0; it < 4; ++it) {
        int p = 4 * (threadIdx.x + it * 256);
        int y = p >> 6, x0 = p & 63;
        bool e0 = (x0 == 0), e3 = (x0 == 60);
        f4u t = *(const f4u*)(SfgTap + bofs + p);
        float s0 = EPSF * t.v[0], s1 = EPSF * t.v[1], s2 = EPSF * t.v[2], s3 = EPSF * t.v[3];
        #pragma unroll
        for (int di = -1; di <= 1; ++di) {
            int ii = i + di, yy = y + di;
            if ((unsigned)ii >= HH || (unsigned)yy >= HH) continue;
            #pragma unroll
            for (int dj = -1; dj <= 1; ++dj) {
                int jj = j + dj;
                if ((unsigned)jj >= WW) continue;
                int D = di * 64 + dj;
                f4u v = *(const f4u*)(M + (size_t)(l + D) * LL + (p + D));
                float v0 = v.v[0], v3 = v.v[3];
                if (dj == -1) v0 = e0 ? 0.f : v0;
                if (dj == 1)  v3 = e3 ? 0.f : v3;
                s0 += v0; s1 += v.v[1]; s2 += v.v[2]; s3 += v3;
            }
        }
        f4u o; o.v[0] = s0 * inl; o.v[1] = s1 * inl; o.v[2] = s2 * inl; o.v[3] = s3 * inl;
        *(f4u*)(sr + p) = o;
    }
    __syncthreads();
    for (int it = 0; it < 4; ++it) {
        int p = 4 * (threadIdx.x + it * 256);
        int y = p >> 6, x0 = p & 63;
        bool e0 = (x0 == 0), e3 = (x0 == 60);
        float b0 = 0.f, b1 = 0.f, b2 = 0.f, b3 = 0.f;
        #pragma unroll
        for (int gy = -1; gy <= 1; ++gy) {
            int yy = y + gy;
            if ((unsigned)yy >= HH) continue;
            int base = (yy << 6) + x0;
            float m1 = sr[base - 1], c0 = sr[base], c1 = sr[base + 1];
            float c2 = sr[base + 2], c3 = sr[base + 3], p4 = sr[base + 4];
            b0 += (e0 ? 0.f : m1) + c0 + c1;
            b1 += c0 + c1 + c2;
            b2 += c1 + c2 + c3;
            b3 += c2 + c3 + (e3 ? 0.f : p4);
        }
        // no-max-sub softmax numerator, row-scaled, quantized to bf16
        u4v o;
        o[0] = f2bf(__expf(b0) * inl); o[1] = f2bf(__expf(b1) * inl);
        o[2] = f2bf(__expf(b2) * inl); o[3] = f2bf(__expf(b3) * inl);
        *(u4v*)(REB + (size_t)l * LL + p) = o;
    }
}

// ---------- K5: plain column sums over bf16 REB: sumc=Σ REB*winv, wsumc=Σ REB ----------
__global__ __launch_bounds__(256) void stats3_kernel(const ushort* __restrict__ REB,
                                                     const float* __restrict__ winv,
                                                     float* __restrict__ sumc,
                                                     float* __restrict__ wsumc, int bofs) {
    int pt = blockIdx.x, ch = blockIdx.y;
    int p = pt * 2048 + threadIdx.x * 8;
    float s[8] = {}, w[8] = {};
    int l0 = ch * (LL / NCH);
    for (int l = l0; l < l0 + LL / NCH; ++l) {
        u4v h0 = *(const u4v*)(REB + (size_t)l * LL + p);
        u4v h1 = *(const u4v*)(REB + (size_t)l * LL + p + 4);
        float wv = winv[bofs + l];
        float v0 = bf2f(h0[0]), v1 = bf2f(h0[1]), v2 = bf2f(h0[2]), v3 = bf2f(h0[3]);
        float v4 = bf2f(h1[0]), v5 = bf2f(h1[1]), v6 = bf2f(h1[2]), v7 = bf2f(h1[3]);
        w[0] += v0; w[1] += v1; w[2] += v2; w[3] += v3;
        w[4] += v4; w[5] += v5; w[6] += v6; w[7] += v7;
        s[0] += v0 * wv; s[1] += v1 * wv; s[2] += v2 * wv; s[3] += v3 * wv;
        s[4] += v4 * wv; s[5] += v5 * wv; s[6] += v6 * wv; s[7] += v7 * wv;
    }
    int idx = ch * LL + p;
    #pragma unroll
    for (int h = 0; h < 2; ++h) {
        f4u so, wo;
        #pragma unroll
        for (int k = 0; k < 4; ++k) { so.v[k] = s[h * 4 + k]; wo.v[k] = w[h * 4 + k]; }
        *(f4u*)(sumc + idx + h * 4) = so;
        *(f4u*)(wsumc + idx + h * 4) = wo;
    }
}

// ---------- K5b: combine chunk sums: isum[p]=1/sumexp; Tp = box(wsum*isum) ----------
__global__ __launch_bounds__(192) void combine_ttap_kernel(const float* __restrict__ sumc,
                                                           const float* __restrict__ wsumc,
                                                           float* __restrict__ isum,
                                                           float* __restrict__ Tp) {
    __shared__ float bs[3][64];
    int yb = blockIdx.x;
    int t = threadIdx.x;              // 0..191
    int r = t >> 6, xcol = t & 63;    // r: row offset (yb-1+r)
    int yy = yb - 1 + r;
    float bv = 0.f;
    if ((unsigned)yy < HH) {
        int p = (yy << 6) + xcol;
        float se = 0.f, ws = 0.f;
        for (int ch = 0; ch < NCH; ++ch) {
            int idx = ch * LL + p;
            se += sumc[idx];
            ws += wsumc[idx];
        }
        float inv = 1.f / se;
        if (r == 1) isum[p] = inv;
        bv = ws * inv;
    }
    bs[r][xcol] = bv;
    __syncthreads();
    if (r == 1) {
        float tt = 0.f;
        #pragma unroll
        for (int rr = 0; rr < 3; ++rr) {
            tt += bs[rr][xcol];
            if (xcol > 0) tt += bs[rr][xcol - 1];
            if (xcol < 63) tt += bs[rr][xcol + 1];
        }
        Tp[(yb << 6) + xcol] = tt;
    }
}

// ---------- K7 v3: fused 9-tap diag stencil + transpose, bf16 LDS for 8 blocks/CU ----------
// block = (i, y, jhalf): 32(j) x 64(x) output subtile of NnT.
// LDS: 3 bands (bf16, isum folded) 13.9KB + T 4.5KB = 18.5KB -> 8 blocks/CU.
__global__ __launch_bounds__(256, 8) void ntile_kernel(const ushort* __restrict__ REB,
                                                       const float* __restrict__ isum,
                                                       ushort* __restrict__ NnT) {
    __shared__ ushort bandH[3][34][68];  // 13.9 KB (row pitch 136B, 8B-aligned)
    __shared__ ushort T[64][36];         // 4.5 KB
    int bid = blockIdx.x;
    int jh = bid & 1;            // j-half
    int y = (bid >> 1) & 63;     // p spatial row
    int i = bid >> 7;            // l spatial row
    int j0 = jh * 32;
    int tid = threadIdx.x;

    // stage 3 diagonal bands (global j rows j0-1 .. j0+32), isum folded, bf16
    #pragma unroll
    for (int di = -1; di <= 1; ++di) {
        int ii = i + di, yy = y + di;
        ushort* dstB = &bandH[di + 1][0][0];
        if ((unsigned)ii >= 64u || (unsigned)yy >= 64u) {
            for (int idx = tid; idx < 34 * 68 / 4; idx += 256) {
                u4v z = {0, 0, 0, 0};
                *(u4v*)(dstB + idx * 4) = z;
            }
            continue;
        }
        const ushort* src = REB + ((size_t)ii * 64) * LL + yy * 64;
        const float* isrc = isum + yy * 64;
        for (int idx = tid; idx < 34 * 8; idx += 256) {
            int r = idx >> 3, cg = (idx & 7) * 8;
            ushort* dst = &bandH[di + 1][r][cg];
            int jg = j0 - 1 + r;            // global j row
            if ((unsigned)jg < 64u) {
                u4v h0 = *(const u4v*)(src + (size_t)jg * LL + cg);
                u4v h1 = *(const u4v*)(src + (size_t)jg * LL + cg + 4);
                f4u w0 = *(const f4u*)(isrc + cg);
                f4u w1 = *(const f4u*)(isrc + cg + 4);
                u4v o0, o1;
                o0[0] = f2bf(bf2f(h0[0]) * w0.v[0]);
                o0[1] = f2bf(bf2f(h0[1]) * w0.v[1]);
                o0[2] = f2bf(bf2f(h0[2]) * w0.v[2]);
                o0[3] = f2bf(bf2f(h0[3]) * w0.v[3]);
                o1[0] = f2bf(bf2f(h1[0]) * w1.v[0]);
                o1[1] = f2bf(bf2f(h1[1]) * w1.v[1]);
                o1[2] = f2bf(bf2f(h1[2]) * w1.v[2]);
                o1[3] = f2bf(bf2f(h1[3]) * w1.v[3]);
                *(u4v*)dst = o0;
                *(u4v*)(dst + 4) = o1;
            } else {
                u4v z = {0, 0, 0, 0};
                *(u4v*)dst = z;
                *(u4v*)(dst + 4) = z;
            }
        }
    }
    __syncthreads();

    // compute: thread = (x = tid&63, jb = tid>>6), 8 j's each
    int x = tid & 63, jb = tid >> 6;
    bool xm1 = (x >= 1), xp1 = (x <= 62);
    float accv[8];
    #pragma unroll
    for (int k = 0; k < 8; ++k) accv[k] = 0.f;
    #pragma unroll
    for (int d3 = 0; d3 < 3; ++d3) {
        const ushort (*B)[68] = bandH[d3];
        #pragma unroll
        for (int k = 0; k < 8; ++k) {
            int jl = jb * 8 + k;       // 0..31
            int j = j0 + jl;           // global j
            int rc = jl + 1;           // band row of center tap
            float s = bf2f(B[rc][x]);
            if (xm1 && j >= 1)  s += bf2f(B[rc - 1][x - 1]);
            if (xp1 && j <= 62) s += bf2f(B[rc + 1][x + 1]);
            accv[k] += s;
        }
    }
    #pragma unroll
    for (int k = 0; k < 8; ++k)
        T[x][jb * 8 + k] = f2bf(accv[k]);
    __syncthreads();

    // coalesced write: NnT row (y*64+xr), cols i*64 + j0 + [0,32)
    int xr = tid >> 2, q4 = tid & 3;
    size_t obase = (size_t)(y * 64 + xr) * LL + i * 64 + j0 + q4 * 8;
    u4v v0 = *(const u4v*)&T[xr][q4 * 8];
    u4v v1 = *(const u4v*)&T[xr][q4 * 8 + 4];
    *(u4v*)(NnT + obase) = v0;
    *(u4v*)(NnT + obase + 4) = v1;
}

// ---------- K9a: partial rec = bgH @ NnT^T over a k-slab, MFMA ----------
__global__ __launch_bounds__(256) void gemm_out_part_mfma(const ushort* __restrict__ bgH,
                                                          const ushort* __restrict__ NnT,
                                                          float* __restrict__ part) {
    int pt = blockIdx.x, ks = blockIdx.y;
    int wid = threadIdx.x >> 6, lane = threadIdx.x & 63;
    int wm = wid >> 1, wn = wid & 1;
    int lm = lane & 15, lk = lane >> 4;
    f4v acc[4][2] = {};
    int arow = wm * 64 + lm;          // c
    int brow = pt * 64 + wn * 32 + lm; // p
    int kbeg = ks * (LL / KS);
    #pragma unroll 2
    for (int k0 = kbeg; k0 < kbeg + LL / KS; k0 += 32) {
        s8v a[4], bq[2];
        #pragma unroll
        for (int f = 0; f < 4; ++f)
            a[f] = *(const s8v*)(bgH + (size_t)(arow + f * 16) * LL + k0 + lk * 8);
        #pragma unroll
        for (int f = 0; f < 2; ++f)
            bq[f] = *(const s8v*)(NnT + (size_t)(brow + f * 16) * LL + k0 + lk * 8);
        #pragma unroll
        for (int mi = 0; mi < 4; ++mi)
            #pragma unroll
            for (int ni = 0; ni < 2; ++ni)
                acc[mi][ni] = __builtin_amdgcn_mfma_f32_16x16x32_bf16(a[mi], bq[ni], acc[mi][ni], 0, 0, 0);
    }
    #pragma unroll
    for (int mi = 0; mi < 4; ++mi)
        #pragma unroll
        for (int ni = 0; ni < 2; ++ni)
            #pragma unroll
            for (int r = 0; r < 4; ++r)
                part[((size_t)ks * CC + wm * 64 + mi * 16 + lk * 4 + r) * LL
                     + pt * 64 + wn * 32 + ni * 16 + lm] = acc[mi][ni][r];
}

// ---------- K9b: combine slabs + epilogue ----------
__global__ void epilogue_kernel(const float* __restrict__ part, const float* __restrict__ Tp,
                                const float* __restrict__ fgb, const float* __restrict__ maskb,
                                float* __restrict__ outb) {
    int g = blockIdx.x * 256 + threadIdx.x;   // C*L
    int p = g & 4095;
    float acc = 0.f;
    for (int ks = 0; ks < KS; ++ks)
        acc += part[(size_t)ks * CC * LL + g];
    float rec = acc + EPSF * Tp[p];
    float mval = maskb[p];
    outb[g] = rec * mval * (1.f / 9.f) + fgb[g] * (1.f - mval);
}

extern "C" void kernel_launch(void* const* d_in, const int* in_sizes, int n_in,
                              void* d_out, int out_size, void* d_ws, size_t ws_size,
                              hipStream_t stream) {
    const float* fg = (const float*)d_in[0];     // [B,C,H,W]
    const float* mask = (const float*)d_in[1];   // [B,1,H,W]
    float* out = (float*)d_out;
    float* ws = (float*)d_ws;

    // ws layout (~134.5 MiB)
    float* Sfg = ws;                                 // B*LL each:
    float* Sbg = Sfg + BB * LL;
    float* Qq = Sbg + BB * LL;
    float* inorm = Qq + BB * LL;
    float* winv = inorm + BB * LL;
    float* SfgTap = winv + BB * LL;
    float* sumc = SfgTap + BB * LL;                  // NCH*LL each:
    float* wsumc = sumc + NCH * LL;
    float* isum = wsumc + NCH * LL;                  // LL each:
    float* Tp = isum + LL;
    ushort* bgH = (ushort*)(Tp + LL);                // B*CC*LL ushorts (4 MiB)
    float* bufA = (float*)(bgH + (size_t)BB * CC * LL);   // LL2 (M, then NnT)
    float* bufB = bufA + LL2;                        // LL2 (REB16 in first half, then part)
    // per-sample transposed bf16 operand tiles live in bufB tail (dead until scoresbox):
    ushort* bgT = (ushort*)(bufB + 8 * 1024 * 1024);
    ushort* fgT = bgT + (size_t)LL * CC;
    // REB bf16 occupies first 32 MB of bufB:
    ushort* REB16 = (ushort*)bufB;
    // after scoresbox, M (bufA) is dead -> reuse for NnT (32 MB):
    ushort* NnT = (ushort*)bufA;
    // after ntile, REB16 (bufB) is dead -> reuse for fp32 partials (16 MB):
    float* part = bufB;

    prep_kernel<<<BB * LL / 256, 256, 0, stream>>>(fg, mask, Sfg, Sbg, Qq);
    norm_kernel<<<BB * LL / 256, 256, 0, stream>>>(Sfg, Sbg, Qq, inorm, winv, SfgTap);

    for (int b = 0; b < BB; ++b) {
        const float* fgb = fg + (size_t)b * CC * LL;
        const float* mb = mask + (size_t)b * LL;
        ushort* bgHb = bgH + (size_t)b * CC * LL;
        int bofs = b * LL;

        transpose_kernel<<<dim3(64, 2), 256, 0, stream>>>(fgb, mb, fgT, bgT, bgHb);
        gemm_M_mfma<<<dim3(32, 32), 256, 0, stream>>>(bgT, fgT, bufA);
        scoresbox_kernel<<<LL, 256, 0, stream>>>(bufA, SfgTap, inorm, REB16, bofs);
        stats3_kernel<<<dim3(2, NCH), 256, 0, stream>>>(REB16, winv, sumc, wsumc, bofs);
        combine_ttap_kernel<<<64, 192, 0, stream>>>(sumc, wsumc, isum, Tp);
        ntile_kernel<<<8192, 256, 0, stream>>>(REB16, isum, NnT);
        gemm_out_part_mfma<<<dim3(64, KS), 256, 0, stream>>>(bgHb, NnT, part);
        epilogue_kernel<<<CC * LL / 256, 256, 0, stream>>>(part, Tp, fgb, mb, out + (size_t)b * CC * LL);
    }
}

// Round 10
// 670.179 us; speedup vs baseline: 1.6623x; 1.0185x over previous
//
#include <hip/hip_runtime.h>
#include <math.h>

#define BB 4
#define CC 128
#define HH 64
#define WW 64
#define LL 4096            // H*W
#define LL2 ((size_t)LL*LL)
#define EPSF 1e-7f
#define NCH 64             // softmax stats chunks over l
#define KS 8               // gemm_out k-slabs

typedef __attribute__((ext_vector_type(8))) short s8v;           // 8 bf16 (4 VGPRs)
typedef __attribute__((ext_vector_type(4))) float f4v;           // 4 fp32
typedef __attribute__((ext_vector_type(4))) unsigned short u4v;  // 4 bf16 (8B)

struct f4u { float v[4]; };
typedef struct __attribute__((packed)) { ushort v[4]; } u4u;     // 2B-aligned 4xbf16

__device__ __forceinline__ ushort f2bf(float f) {
    union { float f; unsigned u; } x; x.f = f;
    unsigned r = x.u + 0x7FFFu + ((x.u >> 16) & 1u);   // RNE
    return (ushort)(r >> 16);
}
__device__ __forceinline__ float bf2f(ushort u) {
    union { unsigned u; float f; } x; x.u = ((unsigned)u) << 16;
    return x.f;
}

// ---------- K1: per-position channel sums ----------
__global__ void prep_kernel(const float* __restrict__ fg, const float* __restrict__ mask,
                            float* __restrict__ Sfg, float* __restrict__ Sbg,
                            float* __restrict__ Qq) {
    int g = blockIdx.x * 256 + threadIdx.x;       // B*L threads
    int b = g >> 12, p = g & (LL - 1);
    float mval = mask[g];
    float s = 0.f, sb = 0.f, q = 0.f;
    const float* f = fg + (size_t)b * CC * LL + p;
    for (int c = 0; c < CC; ++c) {
        float v = f[(size_t)c * LL];
        s += v;
        float bv = v * (1.f - mval);
        sb += bv;
        q += bv * bv;
    }
    Sfg[g] = s; Sbg[g] = sb; Qq[g] = q;
}

// ---------- K2: inorm[l]=1/norm, winv[l]=norm, SfgTap[p]=valid-tap sum of Sfg ----------
__global__ void norm_kernel(const float* __restrict__ Sfg, const float* __restrict__ Sbg,
                            const float* __restrict__ Qq, float* __restrict__ inorm,
                            float* __restrict__ winv, float* __restrict__ SfgTap) {
    int g = blockIdx.x * 256 + threadIdx.x;       // B*L
    int b = g >> 12, l = g & (LL - 1);
    int i = l >> 6, j = l & 63;
    float n2 = 9.f * CC * EPSF * EPSF;
    float st = 0.f;
    for (int di = -1; di <= 1; ++di)
        for (int dj = -1; dj <= 1; ++dj) {
            int ii = i + di, jj = j + dj;
            if (ii >= 0 && ii < HH && jj >= 0 && jj < WW) {
                int idx = (b << 12) + (ii << 6) + jj;
                n2 += Qq[idx] + 2.f * EPSF * Sbg[idx];
                st += Sfg[idx];
            }
        }
    float n = sqrtf(n2);
    inorm[g] = 1.f / n;
    winv[g] = n;
    SfgTap[g] = st;
}

// ---------- K2b: per-sample bf16 copies: fgT/bgT [L][C] (transposed), bgH [C][L] ----------
__global__ __launch_bounds__(256) void transpose_kernel(const float* __restrict__ fgb,
                                                        const float* __restrict__ maskb,
                                                        ushort* __restrict__ fgT,
                                                        ushort* __restrict__ bgT,
                                                        ushort* __restrict__ bgH) {
    __shared__ float tile[64][65];
    int l0 = blockIdx.x * 64, c0 = blockIdx.y * 64;
    int tid = threadIdx.x, col = tid & 63, r0 = tid >> 6;
    for (int r = r0; r < 64; r += 4) {
        float v = fgb[(size_t)(c0 + r) * LL + l0 + col];
        tile[r][col] = v;
        bgH[(size_t)(c0 + r) * LL + l0 + col] = f2bf(v * (1.f - maskb[l0 + col]));
    }
    __syncthreads();
    for (int idx = tid; idx < 4096; idx += 256) {
        int row = idx >> 6;     // l offset
        int c = idx & 63;       // c offset
        float v = tile[c][row];
        size_t o = (size_t)(l0 + row) * CC + c0 + c;
        fgT[o] = f2bf(v);
        bgT[o] = f2bf(v * (1.f - maskb[l0 + row]));
    }
}

// ---------- K3: M (bf16) = bg^T @ fg via MFMA. A=bgT[L][C], B^T=fgT[L][C] ----------
__global__ __launch_bounds__(256) void gemm_M_mfma(const ushort* __restrict__ bgT,
                                                   const ushort* __restrict__ fgT,
                                                   ushort* __restrict__ M16) {
    int lt = blockIdx.y, pt = blockIdx.x;            // 32x32 tiles of 128x128
    int wid = threadIdx.x >> 6, lane = threadIdx.x & 63;
    int wm = wid >> 1, wn = wid & 1;                 // 2x2 waves
    int lm = lane & 15, lk = lane >> 4;
    f4v acc[4][4] = {};
    int arow = lt * 128 + wm * 64 + lm;
    int brow = pt * 128 + wn * 64 + lm;
    for (int k0 = 0; k0 < CC; k0 += 32) {
        s8v a[4], bq[4];
        #pragma unroll
        for (int f = 0; f < 4; ++f)
            a[f] = *(const s8v*)(bgT + (size_t)(arow + f * 16) * CC + k0 + lk * 8);
        #pragma unroll
        for (int f = 0; f < 4; ++f)
            bq[f] = *(const s8v*)(fgT + (size_t)(brow + f * 16) * CC + k0 + lk * 8);
        #pragma unroll
        for (int mi = 0; mi < 4; ++mi)
            #pragma unroll
            for (int ni = 0; ni < 4; ++ni)
                acc[mi][ni] = __builtin_amdgcn_mfma_f32_16x16x32_bf16(a[mi], bq[ni], acc[mi][ni], 0, 0, 0);
    }
    #pragma unroll
    for (int mi = 0; mi < 4; ++mi)
        #pragma unroll
        for (int ni = 0; ni < 4; ++ni)
            #pragma unroll
            for (int r = 0; r < 4; ++r)
                M16[(size_t)(lt * 128 + wm * 64 + mi * 16 + lk * 4 + r) * LL
                    + pt * 128 + wn * 64 + ni * 16 + lm] = f2bf(acc[mi][ni][r]);
}

// ---------- K4: REB[l,:] (bf16) = exp( box_p((9-tap diag-sum of M16 + EPS*SfgTap)*inorm[l]) ) * inorm[l] ----------
__global__ __launch_bounds__(256) void scoresbox_kernel(const ushort* __restrict__ M16,
                                                        const float* __restrict__ SfgTap,
                                                        const float* __restrict__ inorm,
                                                        ushort* __restrict__ REB, int bofs) {
    __shared__ float srow[LL + 136];
    float* sr = srow + 68;
    int l = blockIdx.x;
    int i = l >> 6, j = l & 63;
    float inl = inorm[bofs + l];
    // pass 1: vectorized 9-tap diag sum of bf16 M into LDS row
    for (int it = 0; it < 4; ++it) {
        int p = 4 * (threadIdx.x + it * 256);
        int y = p >> 6, x0 = p & 63;
        bool e0 = (x0 == 0), e3 = (x0 == 60);
        f4u t = *(const f4u*)(SfgTap + bofs + p);
        float s0 = EPSF * t.v[0], s1 = EPSF * t.v[1], s2 = EPSF * t.v[2], s3 = EPSF * t.v[3];
        #pragma unroll
        for (int di = -1; di <= 1; ++di) {
            int ii = i + di, yy = y + di;
            if ((unsigned)ii >= HH || (unsigned)yy >= HH) continue;
            #pragma unroll
            for (int dj = -1; dj <= 1; ++dj) {
                int jj = j + dj;
                if ((unsigned)jj >= WW) continue;
                int D = di * 64 + dj;
                u4u v = *(const u4u*)(M16 + (size_t)(l + D) * LL + (p + D));
                float v0 = bf2f(v.v[0]), v1 = bf2f(v.v[1]), v2 = bf2f(v.v[2]), v3 = bf2f(v.v[3]);
                if (dj == -1) v0 = e0 ? 0.f : v0;
                if (dj == 1)  v3 = e3 ? 0.f : v3;
                s0 += v0; s1 += v1; s2 += v2; s3 += v3;
            }
        }
        f4u o; o.v[0] = s0 * inl; o.v[1] = s1 * inl; o.v[2] = s2 * inl; o.v[3] = s3 * inl;
        *(f4u*)(sr + p) = o;
    }
    __syncthreads();
    // pass 2: scalar-consecutive box over p (conflict-free LDS reads, coalesced 2B writes)
    for (int it = 0; it < 16; ++it) {
        int p = it * 256 + threadIdx.x;
        int y = p >> 6, x0 = p & 63;
        float bs = 0.f;
        #pragma unroll
        for (int gy = -1; gy <= 1; ++gy) {
            int yy = y + gy;
            if ((unsigned)yy >= HH) continue;
            int base = (yy << 6) + x0;
            float s = sr[base];
            if (x0 > 0)  s += sr[base - 1];
            if (x0 < 63) s += sr[base + 1];
            bs += s;
        }
        REB[(size_t)l * LL + p] = f2bf(__expf(bs) * inl);
    }
}

// ---------- K5: plain column sums over bf16 REB: sumc=Σ REB*winv, wsumc=Σ REB ----------
__global__ __launch_bounds__(256) void stats3_kernel(const ushort* __restrict__ REB,
                                                     const float* __restrict__ winv,
                                                     float* __restrict__ sumc,
                                                     float* __restrict__ wsumc, int bofs) {
    int pt = blockIdx.x, ch = blockIdx.y;
    int p = pt * 2048 + threadIdx.x * 8;
    float s[8] = {}, w[8] = {};
    int l0 = ch * (LL / NCH);
    for (int l = l0; l < l0 + LL / NCH; ++l) {
        u4v h0 = *(const u4v*)(REB + (size_t)l * LL + p);
        u4v h1 = *(const u4v*)(REB + (size_t)l * LL + p + 4);
        float wv = winv[bofs + l];
        float v0 = bf2f(h0[0]), v1 = bf2f(h0[1]), v2 = bf2f(h0[2]), v3 = bf2f(h0[3]);
        float v4 = bf2f(h1[0]), v5 = bf2f(h1[1]), v6 = bf2f(h1[2]), v7 = bf2f(h1[3]);
        w[0] += v0; w[1] += v1; w[2] += v2; w[3] += v3;
        w[4] += v4; w[5] += v5; w[6] += v6; w[7] += v7;
        s[0] += v0 * wv; s[1] += v1 * wv; s[2] += v2 * wv; s[3] += v3 * wv;
        s[4] += v4 * wv; s[5] += v5 * wv; s[6] += v6 * wv; s[7] += v7 * wv;
    }
    int idx = ch * LL + p;
    #pragma unroll
    for (int h = 0; h < 2; ++h) {
        f4u so, wo;
        #pragma unroll
        for (int k = 0; k < 4; ++k) { so.v[k] = s[h * 4 + k]; wo.v[k] = w[h * 4 + k]; }
        *(f4u*)(sumc + idx + h * 4) = so;
        *(f4u*)(wsumc + idx + h * 4) = wo;
    }
}

// ---------- K5b: combine chunk sums: isum[p]=1/sumexp; Tp = box(wsum*isum) ----------
__global__ __launch_bounds__(192) void combine_ttap_kernel(const float* __restrict__ sumc,
                                                           const float* __restrict__ wsumc,
                                                           float* __restrict__ isum,
                                                           float* __restrict__ Tp) {
    __shared__ float bs[3][64];
    int yb = blockIdx.x;
    int t = threadIdx.x;              // 0..191
    int r = t >> 6, xcol = t & 63;    // r: row offset (yb-1+r)
    int yy = yb - 1 + r;
    float bv = 0.f;
    if ((unsigned)yy < HH) {
        int p = (yy << 6) + xcol;
        float se = 0.f, ws = 0.f;
        for (int ch = 0; ch < NCH; ++ch) {
            int idx = ch * LL + p;
            se += sumc[idx];
            ws += wsumc[idx];
        }
        float inv = 1.f / se;
        if (r == 1) isum[p] = inv;
        bv = ws * inv;
    }
    bs[r][xcol] = bv;
    __syncthreads();
    if (r == 1) {
        float tt = 0.f;
        #pragma unroll
        for (int rr = 0; rr < 3; ++rr) {
            tt += bs[rr][xcol];
            if (xcol > 0) tt += bs[rr][xcol - 1];
            if (xcol < 63) tt += bs[rr][xcol + 1];
        }
        Tp[(yb << 6) + xcol] = tt;
    }
}

// ---------- K7 v3: fused 9-tap diag stencil + transpose, bf16 LDS for 8 blocks/CU ----------
__global__ __launch_bounds__(256, 8) void ntile_kernel(const ushort* __restrict__ REB,
                                                       const float* __restrict__ isum,
                                                       ushort* __restrict__ NnT) {
    __shared__ ushort bandH[3][34][68];  // 13.9 KB (row pitch 136B, 8B-aligned)
    __shared__ ushort T[64][36];         // 4.5 KB
    int bid = blockIdx.x;
    int jh = bid & 1;            // j-half
    int y = (bid >> 1) & 63;     // p spatial row
    int i = bid >> 7;            // l spatial row
    int j0 = jh * 32;
    int tid = threadIdx.x;

    #pragma unroll
    for (int di = -1; di <= 1; ++di) {
        int ii = i + di, yy = y + di;
        ushort* dstB = &bandH[di + 1][0][0];
        if ((unsigned)ii >= 64u || (unsigned)yy >= 64u) {
            for (int idx = tid; idx < 34 * 68 / 4; idx += 256) {
                u4v z = {0, 0, 0, 0};
                *(u4v*)(dstB + idx * 4) = z;
            }
            continue;
        }
        const ushort* src = REB + ((size_t)ii * 64) * LL + yy * 64;
        const float* isrc = isum + yy * 64;
        for (int idx = tid; idx < 34 * 8; idx += 256) {
            int r = idx >> 3, cg = (idx & 7) * 8;
            ushort* dst = &bandH[di + 1][r][cg];
            int jg = j0 - 1 + r;            // global j row
            if ((unsigned)jg < 64u) {
                u4v h0 = *(const u4v*)(src + (size_t)jg * LL + cg);
                u4v h1 = *(const u4v*)(src + (size_t)jg * LL + cg + 4);
                f4u w0 = *(const f4u*)(isrc + cg);
                f4u w1 = *(const f4u*)(isrc + cg + 4);
                u4v o0, o1;
                o0[0] = f2bf(bf2f(h0[0]) * w0.v[0]);
                o0[1] = f2bf(bf2f(h0[1]) * w0.v[1]);
                o0[2] = f2bf(bf2f(h0[2]) * w0.v[2]);
                o0[3] = f2bf(bf2f(h0[3]) * w0.v[3]);
                o1[0] = f2bf(bf2f(h1[0]) * w1.v[0]);
                o1[1] = f2bf(bf2f(h1[1]) * w1.v[1]);
                o1[2] = f2bf(bf2f(h1[2]) * w1.v[2]);
                o1[3] = f2bf(bf2f(h1[3]) * w1.v[3]);
                *(u4v*)dst = o0;
                *(u4v*)(dst + 4) = o1;
            } else {
                u4v z = {0, 0, 0, 0};
                *(u4v*)dst = z;
                *(u4v*)(dst + 4) = z;
            }
        }
    }
    __syncthreads();

    int x = tid & 63, jb = tid >> 6;
    bool xm1 = (x >= 1), xp1 = (x <= 62);
    float accv[8];
    #pragma unroll
    for (int k = 0; k < 8; ++k) accv[k] = 0.f;
    #pragma unroll
    for (int d3 = 0; d3 < 3; ++d3) {
        const ushort (*B)[68] = bandH[d3];
        #pragma unroll
        for (int k = 0; k < 8; ++k) {
            int jl = jb * 8 + k;       // 0..31
            int j = j0 + jl;           // global j
            int rc = jl + 1;           // band row of center tap
            float s = bf2f(B[rc][x]);
            if (xm1 && j >= 1)  s += bf2f(B[rc - 1][x - 1]);
            if (xp1 && j <= 62) s += bf2f(B[rc + 1][x + 1]);
            accv[k] += s;
        }
    }
    #pragma unroll
    for (int k = 0; k < 8; ++k)
        T[x][jb * 8 + k] = f2bf(accv[k]);
    __syncthreads();

    int xr = tid >> 2, q4 = tid & 3;
    size_t obase = (size_t)(y * 64 + xr) * LL + i * 64 + j0 + q4 * 8;
    u4v v0 = *(const u4v*)&T[xr][q4 * 8];
    u4v v1 = *(const u4v*)&T[xr][q4 * 8 + 4];
    *(u4v*)(NnT + obase) = v0;
    *(u4v*)(NnT + obase + 4) = v1;
}

// ---------- K9a: partial rec = bgH @ NnT^T over a k-slab, MFMA ----------
__global__ __launch_bounds__(256) void gemm_out_part_mfma(const ushort* __restrict__ bgH,
                                                          const ushort* __restrict__ NnT,
                                                          float* __restrict__ part) {
    int pt = blockIdx.x, ks = blockIdx.y;
    int wid = threadIdx.x >> 6, lane = threadIdx.x & 63;
    int wm = wid >> 1, wn = wid & 1;
    int lm = lane & 15, lk = lane >> 4;
    f4v acc[4][2] = {};
    int arow = wm * 64 + lm;          // c
    int brow = pt * 64 + wn * 32 + lm; // p
    int kbeg = ks * (LL / KS);
    #pragma unroll 2
    for (int k0 = kbeg; k0 < kbeg + LL / KS; k0 += 32) {
        s8v a[4], bq[2];
        #pragma unroll
        for (int f = 0; f < 4; ++f)
            a[f] = *(const s8v*)(bgH + (size_t)(arow + f * 16) * LL + k0 + lk * 8);
        #pragma unroll
        for (int f = 0; f < 2; ++f)
            bq[f] = *(const s8v*)(NnT + (size_t)(brow + f * 16) * LL + k0 + lk * 8);
        #pragma unroll
        for (int mi = 0; mi < 4; ++mi)
            #pragma unroll
            for (int ni = 0; ni < 2; ++ni)
                acc[mi][ni] = __builtin_amdgcn_mfma_f32_16x16x32_bf16(a[mi], bq[ni], acc[mi][ni], 0, 0, 0);
    }
    #pragma unroll
    for (int mi = 0; mi < 4; ++mi)
        #pragma unroll
        for (int ni = 0; ni < 2; ++ni)
            #pragma unroll
            for (int r = 0; r < 4; ++r)
                part[((size_t)ks * CC + wm * 64 + mi * 16 + lk * 4 + r) * LL
                     + pt * 64 + wn * 32 + ni * 16 + lm] = acc[mi][ni][r];
}

// ---------- K9b: combine slabs + epilogue ----------
__global__ void epilogue_kernel(const float* __restrict__ part, const float* __restrict__ Tp,
                                const float* __restrict__ fgb, const float* __restrict__ maskb,
                                float* __restrict__ outb) {
    int g = blockIdx.x * 256 + threadIdx.x;   // C*L
    int p = g & 4095;
    float acc = 0.f;
    for (int ks = 0; ks < KS; ++ks)
        acc += part[(size_t)ks * CC * LL + g];
    float rec = acc + EPSF * Tp[p];
    float mval = maskb[p];
    outb[g] = rec * mval * (1.f / 9.f) + fgb[g] * (1.f - mval);
}

extern "C" void kernel_launch(void* const* d_in, const int* in_sizes, int n_in,
                              void* d_out, int out_size, void* d_ws, size_t ws_size,
                              hipStream_t stream) {
    const float* fg = (const float*)d_in[0];     // [B,C,H,W]
    const float* mask = (const float*)d_in[1];   // [B,1,H,W]
    float* out = (float*)d_out;
    float* ws = (float*)d_ws;

    // ws layout (~134.5 MiB)
    float* Sfg = ws;                                 // B*LL each:
    float* Sbg = Sfg + BB * LL;
    float* Qq = Sbg + BB * LL;
    float* inorm = Qq + BB * LL;
    float* winv = inorm + BB * LL;
    float* SfgTap = winv + BB * LL;
    float* sumc = SfgTap + BB * LL;                  // NCH*LL each:
    float* wsumc = sumc + NCH * LL;
    float* isum = wsumc + NCH * LL;                  // LL each:
    float* Tp = isum + LL;
    ushort* bgH = (ushort*)(Tp + LL);                // B*CC*LL ushorts (4 MiB)
    float* bufA = (float*)(bgH + (size_t)BB * CC * LL);   // LL2 (M16, then NnT)
    float* bufB = bufA + LL2;                        // LL2 (REB16 in first half, then part)
    // per-sample transposed bf16 operand tiles live in bufB tail (dead until scoresbox):
    ushort* bgT = (ushort*)(bufB + 8 * 1024 * 1024);
    ushort* fgT = bgT + (size_t)LL * CC;
    // M bf16 occupies first 32 MB of bufA; NnT reuses the same region after scoresbox:
    ushort* M16 = (ushort*)bufA;
    ushort* NnT = (ushort*)bufA;
    // REB bf16 occupies first 32 MB of bufB:
    ushort* REB16 = (ushort*)bufB;
    // after ntile, REB16 (bufB) is dead -> reuse for fp32 partials (16 MB):
    float* part = bufB;

    prep_kernel<<<BB * LL / 256, 256, 0, stream>>>(fg, mask, Sfg, Sbg, Qq);
    norm_kernel<<<BB * LL / 256, 256, 0, stream>>>(Sfg, Sbg, Qq, inorm, winv, SfgTap);

    for (int b = 0; b < BB; ++b) {
        const float* fgb = fg + (size_t)b * CC * LL;
        const float* mb = mask + (size_t)b * LL;
        ushort* bgHb = bgH + (size_t)b * CC * LL;
        int bofs = b * LL;

        transpose_kernel<<<dim3(64, 2), 256, 0, stream>>>(fgb, mb, fgT, bgT, bgHb);
        gemm_M_mfma<<<dim3(32, 32), 256, 0, stream>>>(bgT, fgT, M16);
        scoresbox_kernel<<<LL, 256, 0, stream>>>(M16, SfgTap, inorm, REB16, bofs);
        stats3_kernel<<<dim3(2, NCH), 256, 0, stream>>>(REB16, winv, sumc, wsumc, bofs);
        combine_ttap_kernel<<<64, 192, 0, stream>>>(sumc, wsumc, isum, Tp);
        ntile_kernel<<<8192, 256, 0, stream>>>(REB16, isum, NnT);
        gemm_out_part_mfma<<<dim3(64, KS), 256, 0, stream>>>(bgHb, NnT, part);
        epilogue_kernel<<<CC * LL / 256, 256, 0, stream>>>(part, Tp, fgb, mb, out + (size_t)b * CC * LL);
    }
}

// Round 11
// 645.314 us; speedup vs baseline: 1.7264x; 1.0385x over previous
//
#include <hip/hip_runtime.h>
#include <math.h>

#define BB 4
#define CC 128
#define HH 64
#define WW 64
#define LL 4096            // H*W
#define LL2 ((size_t)LL*LL)
#define EPSF 1e-7f
#define NCH 64             // softmax stats chunks over l
#define KS 8               // gemm_out k-slabs

typedef __attribute__((ext_vector_type(8))) short s8v;           // 8 bf16 (4 VGPRs)
typedef __attribute__((ext_vector_type(4))) float f4v;           // 4 fp32
typedef __attribute__((ext_vector_type(4))) unsigned short u4v;  // 4 bf16 (8B)

struct f4u { float v[4]; };

__device__ __forceinline__ ushort f2bf(float f) {
    union { float f; unsigned u; } x; x.f = f;
    unsigned r = x.u + 0x7FFFu + ((x.u >> 16) & 1u);   // RNE
    return (ushort)(r >> 16);
}
__device__ __forceinline__ float bf2f(ushort u) {
    union { unsigned u; float f; } x; x.u = ((unsigned)u) << 16;
    return x.f;
}

// ---------- K1: per-position channel sums ----------
__global__ void prep_kernel(const float* __restrict__ fg, const float* __restrict__ mask,
                            float* __restrict__ Sfg, float* __restrict__ Sbg,
                            float* __restrict__ Qq) {
    int g = blockIdx.x * 256 + threadIdx.x;       // B*L threads
    int b = g >> 12, p = g & (LL - 1);
    float mval = mask[g];
    float s = 0.f, sb = 0.f, q = 0.f;
    const float* f = fg + (size_t)b * CC * LL + p;
    for (int c = 0; c < CC; ++c) {
        float v = f[(size_t)c * LL];
        s += v;
        float bv = v * (1.f - mval);
        sb += bv;
        q += bv * bv;
    }
    Sfg[g] = s; Sbg[g] = sb; Qq[g] = q;
}

// ---------- K2: inorm[l]=1/norm, winv[l]=norm, SfgTap[p]=valid-tap sum of Sfg ----------
__global__ void norm_kernel(const float* __restrict__ Sfg, const float* __restrict__ Sbg,
                            const float* __restrict__ Qq, float* __restrict__ inorm,
                            float* __restrict__ winv, float* __restrict__ SfgTap) {
    int g = blockIdx.x * 256 + threadIdx.x;       // B*L
    int b = g >> 12, l = g & (LL - 1);
    int i = l >> 6, j = l & 63;
    float n2 = 9.f * CC * EPSF * EPSF;
    float st = 0.f;
    for (int di = -1; di <= 1; ++di)
        for (int dj = -1; dj <= 1; ++dj) {
            int ii = i + di, jj = j + dj;
            if (ii >= 0 && ii < HH && jj >= 0 && jj < WW) {
                int idx = (b << 12) + (ii << 6) + jj;
                n2 += Qq[idx] + 2.f * EPSF * Sbg[idx];
                st += Sfg[idx];
            }
        }
    float n = sqrtf(n2);
    inorm[g] = 1.f / n;
    winv[g] = n;
    SfgTap[g] = st;
}

// ---------- K2b: per-sample bf16 copies: fgT/bgT [L][C] (transposed), bgH [C][L] ----------
__global__ __launch_bounds__(256) void transpose_kernel(const float* __restrict__ fgb,
                                                        const float* __restrict__ maskb,
                                                        ushort* __restrict__ fgT,
                                                        ushort* __restrict__ bgT,
                                                        ushort* __restrict__ bgH) {
    __shared__ float tile[64][65];
    int l0 = blockIdx.x * 64, c0 = blockIdx.y * 64;
    int tid = threadIdx.x, col = tid & 63, r0 = tid >> 6;
    for (int r = r0; r < 64; r += 4) {
        float v = fgb[(size_t)(c0 + r) * LL + l0 + col];
        tile[r][col] = v;
        bgH[(size_t)(c0 + r) * LL + l0 + col] = f2bf(v * (1.f - maskb[l0 + col]));
    }
    __syncthreads();
    for (int idx = tid; idx < 4096; idx += 256) {
        int row = idx >> 6;     // l offset
        int c = idx & 63;       // c offset
        float v = tile[c][row];
        size_t o = (size_t)(l0 + row) * CC + c0 + c;
        fgT[o] = f2bf(v);
        bgT[o] = f2bf(v * (1.f - maskb[l0 + row]));
    }
}

// ---------- K3: M (bf16) = bg^T @ fg via MFMA. A=bgT[L][C], B^T=fgT[L][C] ----------
__global__ __launch_bounds__(256) void gemm_M_mfma(const ushort* __restrict__ bgT,
                                                   const ushort* __restrict__ fgT,
                                                   ushort* __restrict__ M16) {
    int lt = blockIdx.y, pt = blockIdx.x;            // 32x32 tiles of 128x128
    int wid = threadIdx.x >> 6, lane = threadIdx.x & 63;
    int wm = wid >> 1, wn = wid & 1;                 // 2x2 waves
    int lm = lane & 15, lk = lane >> 4;
    f4v acc[4][4] = {};
    int arow = lt * 128 + wm * 64 + lm;
    int brow = pt * 128 + wn * 64 + lm;
    for (int k0 = 0; k0 < CC; k0 += 32) {
        s8v a[4], bq[4];
        #pragma unroll
        for (int f = 0; f < 4; ++f)
            a[f] = *(const s8v*)(bgT + (size_t)(arow + f * 16) * CC + k0 + lk * 8);
        #pragma unroll
        for (int f = 0; f < 4; ++f)
            bq[f] = *(const s8v*)(fgT + (size_t)(brow + f * 16) * CC + k0 + lk * 8);
        #pragma unroll
        for (int mi = 0; mi < 4; ++mi)
            #pragma unroll
            for (int ni = 0; ni < 4; ++ni)
                acc[mi][ni] = __builtin_amdgcn_mfma_f32_16x16x32_bf16(a[mi], bq[ni], acc[mi][ni], 0, 0, 0);
    }
    #pragma unroll
    for (int mi = 0; mi < 4; ++mi)
        #pragma unroll
        for (int ni = 0; ni < 4; ++ni)
            #pragma unroll
            for (int r = 0; r < 4; ++r)
                M16[(size_t)(lt * 128 + wm * 64 + mi * 16 + lk * 4 + r) * LL
                    + pt * 128 + wn * 64 + ni * 16 + lm] = f2bf(acc[mi][ni][r]);
}

// ---------- K4 v4: REB[l,:] (bf16). Pass1: aligned register-shift tap loads. ----------
// tap (di,dj): row (i+di)*64 + (j+dj), cols p+di*64+dj -> aligned u4v pair + 1 edge scalar.
__global__ __launch_bounds__(256) void scoresbox_kernel(const ushort* __restrict__ M16,
                                                        const float* __restrict__ SfgTap,
                                                        const float* __restrict__ inorm,
                                                        ushort* __restrict__ REB, int bofs) {
    __shared__ float srow[LL];
    int l = blockIdx.x;
    int i = l >> 6, j = l & 63;
    float inl = inorm[bofs + l];
    float linl = __logf(inl);
    bool jm = (j >= 1), jp = (j <= 62);
    // pass 1: raw 9-tap diag sums (inl deferred; box is linear, inl block-constant)
    #pragma unroll
    for (int it = 0; it < 2; ++it) {
        int p8 = 8 * (threadIdx.x + it * 256);
        int y = p8 >> 6, x0 = p8 & 63;
        f4u t0 = *(const f4u*)(SfgTap + bofs + p8);
        f4u t1 = *(const f4u*)(SfgTap + bofs + p8 + 4);
        float acc[8];
        acc[0] = EPSF * t0.v[0]; acc[1] = EPSF * t0.v[1];
        acc[2] = EPSF * t0.v[2]; acc[3] = EPSF * t0.v[3];
        acc[4] = EPSF * t1.v[0]; acc[5] = EPSF * t1.v[1];
        acc[6] = EPSF * t1.v[2]; acc[7] = EPSF * t1.v[3];
        #pragma unroll
        for (int di = -1; di <= 1; ++di) {
            int ii = i + di, yy = y + di;
            if ((unsigned)ii >= HH || (unsigned)yy >= HH) continue;
            int rb = ii * 64;                       // row-block base
            size_t cb = (size_t)(p8 + di * 64);     // aligned col base
            {   // dj = 0
                const ushort* rw = M16 + (size_t)(rb + j) * LL + cb;
                u4v c0 = *(const u4v*)rw, c1 = *(const u4v*)(rw + 4);
                acc[0] += bf2f(c0[0]); acc[1] += bf2f(c0[1]);
                acc[2] += bf2f(c0[2]); acc[3] += bf2f(c0[3]);
                acc[4] += bf2f(c1[0]); acc[5] += bf2f(c1[1]);
                acc[6] += bf2f(c1[2]); acc[7] += bf2f(c1[3]);
            }
            if (jm) {   // dj = -1: vals = [edge, c0..c6]
                const ushort* rw = M16 + (size_t)(rb + j - 1) * LL + cb;
                u4v c0 = *(const u4v*)rw, c1 = *(const u4v*)(rw + 4);
                float lm = (x0 > 0) ? bf2f(rw[-1]) : 0.f;
                acc[0] += lm;          acc[1] += bf2f(c0[0]);
                acc[2] += bf2f(c0[1]); acc[3] += bf2f(c0[2]);
                acc[4] += bf2f(c0[3]); acc[5] += bf2f(c1[0]);
                acc[6] += bf2f(c1[1]); acc[7] += bf2f(c1[2]);
            }
            if (jp) {   // dj = +1: vals = [c1..c7, edge]
                const ushort* rw = M16 + (size_t)(rb + j + 1) * LL + cb;
                u4v c0 = *(const u4v*)rw, c1 = *(const u4v*)(rw + 4);
                float rm = (x0 < 56) ? bf2f(rw[8]) : 0.f;
                acc[0] += bf2f(c0[1]); acc[1] += bf2f(c0[2]);
                acc[2] += bf2f(c0[3]); acc[3] += bf2f(c1[0]);
                acc[4] += bf2f(c1[1]); acc[5] += bf2f(c1[2]);
                acc[6] += bf2f(c1[3]); acc[7] += rm;
            }
        }
        f4u o0, o1;
        o0.v[0] = acc[0]; o0.v[1] = acc[1]; o0.v[2] = acc[2]; o0.v[3] = acc[3];
        o1.v[0] = acc[4]; o1.v[1] = acc[5]; o1.v[2] = acc[6]; o1.v[3] = acc[7];
        *(f4u*)(srow + p8) = o0;
        *(f4u*)(srow + p8 + 4) = o1;
    }
    __syncthreads();
    // pass 2: scalar-consecutive box over p; REB = exp(bs*inl + log(inl))
    for (int it = 0; it < 16; ++it) {
        int p = it * 256 + threadIdx.x;
        int y = p >> 6, x0 = p & 63;
        float bs = 0.f;
        #pragma unroll
        for (int gy = -1; gy <= 1; ++gy) {
            int yy = y + gy;
            if ((unsigned)yy >= HH) continue;
            int base = (yy << 6) + x0;
            float s = srow[base];
            if (x0 > 0)  s += srow[base - 1];
            if (x0 < 63) s += srow[base + 1];
            bs += s;
        }
        REB[(size_t)l * LL + p] = f2bf(__expf(fmaf(bs, inl, linl)));
    }
}

// ---------- K5: plain column sums over bf16 REB: sumc=Σ REB*winv, wsumc=Σ REB ----------
__global__ __launch_bounds__(256) void stats3_kernel(const ushort* __restrict__ REB,
                                                     const float* __restrict__ winv,
                                                     float* __restrict__ sumc,
                                                     float* __restrict__ wsumc, int bofs) {
    int pt = blockIdx.x, ch = blockIdx.y;
    int p = pt * 2048 + threadIdx.x * 8;
    float s[8] = {}, w[8] = {};
    int l0 = ch * (LL / NCH);
    for (int l = l0; l < l0 + LL / NCH; ++l) {
        u4v h0 = *(const u4v*)(REB + (size_t)l * LL + p);
        u4v h1 = *(const u4v*)(REB + (size_t)l * LL + p + 4);
        float wv = winv[bofs + l];
        float v0 = bf2f(h0[0]), v1 = bf2f(h0[1]), v2 = bf2f(h0[2]), v3 = bf2f(h0[3]);
        float v4 = bf2f(h1[0]), v5 = bf2f(h1[1]), v6 = bf2f(h1[2]), v7 = bf2f(h1[3]);
        w[0] += v0; w[1] += v1; w[2] += v2; w[3] += v3;
        w[4] += v4; w[5] += v5; w[6] += v6; w[7] += v7;
        s[0] += v0 * wv; s[1] += v1 * wv; s[2] += v2 * wv; s[3] += v3 * wv;
        s[4] += v4 * wv; s[5] += v5 * wv; s[6] += v6 * wv; s[7] += v7 * wv;
    }
    int idx = ch * LL + p;
    #pragma unroll
    for (int h = 0; h < 2; ++h) {
        f4u so, wo;
        #pragma unroll
        for (int k = 0; k < 4; ++k) { so.v[k] = s[h * 4 + k]; wo.v[k] = w[h * 4 + k]; }
        *(f4u*)(sumc + idx + h * 4) = so;
        *(f4u*)(wsumc + idx + h * 4) = wo;
    }
}

// ---------- K5b: combine chunk sums: isum[p]=1/sumexp; Tp = box(wsum*isum) ----------
__global__ __launch_bounds__(192) void combine_ttap_kernel(const float* __restrict__ sumc,
                                                           const float* __restrict__ wsumc,
                                                           float* __restrict__ isum,
                                                           float* __restrict__ Tp) {
    __shared__ float bs[3][64];
    int yb = blockIdx.x;
    int t = threadIdx.x;              // 0..191
    int r = t >> 6, xcol = t & 63;    // r: row offset (yb-1+r)
    int yy = yb - 1 + r;
    float bv = 0.f;
    if ((unsigned)yy < HH) {
        int p = (yy << 6) + xcol;
        float se = 0.f, ws = 0.f;
        for (int ch = 0; ch < NCH; ++ch) {
            int idx = ch * LL + p;
            se += sumc[idx];
            ws += wsumc[idx];
        }
        float inv = 1.f / se;
        if (r == 1) isum[p] = inv;
        bv = ws * inv;
    }
    bs[r][xcol] = bv;
    __syncthreads();
    if (r == 1) {
        float tt = 0.f;
        #pragma unroll
        for (int rr = 0; rr < 3; ++rr) {
            tt += bs[rr][xcol];
            if (xcol > 0) tt += bs[rr][xcol - 1];
            if (xcol < 63) tt += bs[rr][xcol + 1];
        }
        Tp[(yb << 6) + xcol] = tt;
    }
}

// ---------- K7 v3: fused 9-tap diag stencil + transpose, bf16 LDS for 8 blocks/CU ----------
__global__ __launch_bounds__(256, 8) void ntile_kernel(const ushort* __restrict__ REB,
                                                       const float* __restrict__ isum,
                                                       ushort* __restrict__ NnT) {
    __shared__ ushort bandH[3][34][68];  // 13.9 KB (row pitch 136B, 8B-aligned)
    __shared__ ushort T[64][36];         // 4.5 KB
    int bid = blockIdx.x;
    int jh = bid & 1;            // j-half
    int y = (bid >> 1) & 63;     // p spatial row
    int i = bid >> 7;            // l spatial row
    int j0 = jh * 32;
    int tid = threadIdx.x;

    #pragma unroll
    for (int di = -1; di <= 1; ++di) {
        int ii = i + di, yy = y + di;
        ushort* dstB = &bandH[di + 1][0][0];
        if ((unsigned)ii >= 64u || (unsigned)yy >= 64u) {
            for (int idx = tid; idx < 34 * 68 / 4; idx += 256) {
                u4v z = {0, 0, 0, 0};
                *(u4v*)(dstB + idx * 4) = z;
            }
            continue;
        }
        const ushort* src = REB + ((size_t)ii * 64) * LL + yy * 64;
        const float* isrc = isum + yy * 64;
        for (int idx = tid; idx < 34 * 8; idx += 256) {
            int r = idx >> 3, cg = (idx & 7) * 8;
            ushort* dst = &bandH[di + 1][r][cg];
            int jg = j0 - 1 + r;            // global j row
            if ((unsigned)jg < 64u) {
                u4v h0 = *(const u4v*)(src + (size_t)jg * LL + cg);
                u4v h1 = *(const u4v*)(src + (size_t)jg * LL + cg + 4);
                f4u w0 = *(const f4u*)(isrc + cg);
                f4u w1 = *(const f4u*)(isrc + cg + 4);
                u4v o0, o1;
                o0[0] = f2bf(bf2f(h0[0]) * w0.v[0]);
                o0[1] = f2bf(bf2f(h0[1]) * w0.v[1]);
                o0[2] = f2bf(bf2f(h0[2]) * w0.v[2]);
                o0[3] = f2bf(bf2f(h0[3]) * w0.v[3]);
                o1[0] = f2bf(bf2f(h1[0]) * w1.v[0]);
                o1[1] = f2bf(bf2f(h1[1]) * w1.v[1]);
                o1[2] = f2bf(bf2f(h1[2]) * w1.v[2]);
                o1[3] = f2bf(bf2f(h1[3]) * w1.v[3]);
                *(u4v*)dst = o0;
                *(u4v*)(dst + 4) = o1;
            } else {
                u4v z = {0, 0, 0, 0};
                *(u4v*)dst = z;
                *(u4v*)(dst + 4) = z;
            }
        }
    }
    __syncthreads();

    int x = tid & 63, jb = tid >> 6;
    bool xm1 = (x >= 1), xp1 = (x <= 62);
    float accv[8];
    #pragma unroll
    for (int k = 0; k < 8; ++k) accv[k] = 0.f;
    #pragma unroll
    for (int d3 = 0; d3 < 3; ++d3) {
        const ushort (*B)[68] = bandH[d3];
        #pragma unroll
        for (int k = 0; k < 8; ++k) {
            int jl = jb * 8 + k;       // 0..31
            int j = j0 + jl;           // global j
            int rc = jl + 1;           // band row of center tap
            float s = bf2f(B[rc][x]);
            if (xm1 && j >= 1)  s += bf2f(B[rc - 1][x - 1]);
            if (xp1 && j <= 62) s += bf2f(B[rc + 1][x + 1]);
            accv[k] += s;
        }
    }
    #pragma unroll
    for (int k = 0; k < 8; ++k)
        T[x][jb * 8 + k] = f2bf(accv[k]);
    __syncthreads();

    int xr = tid >> 2, q4 = tid & 3;
    size_t obase = (size_t)(y * 64 + xr) * LL + i * 64 + j0 + q4 * 8;
    u4v v0 = *(const u4v*)&T[xr][q4 * 8];
    u4v v1 = *(const u4v*)&T[xr][q4 * 8 + 4];
    *(u4v*)(NnT + obase) = v0;
    *(u4v*)(NnT + obase + 4) = v1;
}

// ---------- K9a: partial rec = bgH @ NnT^T over a k-slab, MFMA ----------
__global__ __launch_bounds__(256) void gemm_out_part_mfma(const ushort* __restrict__ bgH,
                                                          const ushort* __restrict__ NnT,
                                                          float* __restrict__ part) {
    int pt = blockIdx.x, ks = blockIdx.y;
    int wid = threadIdx.x >> 6, lane = threadIdx.x & 63;
    int wm = wid >> 1, wn = wid & 1;
    int lm = lane & 15, lk = lane >> 4;
    f4v acc[4][2] = {};
    int arow = wm * 64 + lm;          // c
    int brow = pt * 64 + wn * 32 + lm; // p
    int kbeg = ks * (LL / KS);
    #pragma unroll 2
    for (int k0 = kbeg; k0 < kbeg + LL / KS; k0 += 32) {
        s8v a[4], bq[2];
        #pragma unroll
        for (int f = 0; f < 4; ++f)
            a[f] = *(const s8v*)(bgH + (size_t)(arow + f * 16) * LL + k0 + lk * 8);
        #pragma unroll
        for (int f = 0; f < 2; ++f)
            bq[f] = *(const s8v*)(NnT + (size_t)(brow + f * 16) * LL + k0 + lk * 8);
        #pragma unroll
        for (int mi = 0; mi < 4; ++mi)
            #pragma unroll
            for (int ni = 0; ni < 2; ++ni)
                acc[mi][ni] = __builtin_amdgcn_mfma_f32_16x16x32_bf16(a[mi], bq[ni], acc[mi][ni], 0, 0, 0);
    }
    #pragma unroll
    for (int mi = 0; mi < 4; ++mi)
        #pragma unroll
        for (int ni = 0; ni < 2; ++ni)
            #pragma unroll
            for (int r = 0; r < 4; ++r)
                part[((size_t)ks * CC + wm * 64 + mi * 16 + lk * 4 + r) * LL
                     + pt * 64 + wn * 32 + ni * 16 + lm] = acc[mi][ni][r];
}

// ---------- K9b: combine slabs + epilogue ----------
__global__ void epilogue_kernel(const float* __restrict__ part, const float* __restrict__ Tp,
                                const float* __restrict__ fgb, const float* __restrict__ maskb,
                                float* __restrict__ outb) {
    int g = blockIdx.x * 256 + threadIdx.x;   // C*L
    int p = g & 4095;
    float acc = 0.f;
    for (int ks = 0; ks < KS; ++ks)
        acc += part[(size_t)ks * CC * LL + g];
    float rec = acc + EPSF * Tp[p];
    float mval = maskb[p];
    outb[g] = rec * mval * (1.f / 9.f) + fgb[g] * (1.f - mval);
}

extern "C" void kernel_launch(void* const* d_in, const int* in_sizes, int n_in,
                              void* d_out, int out_size, void* d_ws, size_t ws_size,
                              hipStream_t stream) {
    const float* fg = (const float*)d_in[0];     // [B,C,H,W]
    const float* mask = (const float*)d_in[1];   // [B,1,H,W]
    float* out = (float*)d_out;
    float* ws = (float*)d_ws;

    // ws layout (~134.5 MiB)
    float* Sfg = ws;                                 // B*LL each:
    float* Sbg = Sfg + BB * LL;
    float* Qq = Sbg + BB * LL;
    float* inorm = Qq + BB * LL;
    float* winv = inorm + BB * LL;
    float* SfgTap = winv + BB * LL;
    float* sumc = SfgTap + BB * LL;                  // NCH*LL each:
    float* wsumc = sumc + NCH * LL;
    float* isum = wsumc + NCH * LL;                  // LL each:
    float* Tp = isum + LL;
    ushort* bgH = (ushort*)(Tp + LL);                // B*CC*LL ushorts (4 MiB)
    float* bufA = (float*)(bgH + (size_t)BB * CC * LL);   // LL2 (M16, then NnT)
    float* bufB = bufA + LL2;                        // LL2 (REB16 in first half, then part)
    // per-sample transposed bf16 operand tiles live in bufB tail (dead until scoresbox):
    ushort* bgT = (ushort*)(bufB + 8 * 1024 * 1024);
    ushort* fgT = bgT + (size_t)LL * CC;
    // M bf16 occupies first 32 MB of bufA; NnT reuses the same region after scoresbox:
    ushort* M16 = (ushort*)bufA;
    ushort* NnT = (ushort*)bufA;
    // REB bf16 occupies first 32 MB of bufB:
    ushort* REB16 = (ushort*)bufB;
    // after ntile, REB16 (bufB) is dead -> reuse for fp32 partials (16 MB):
    float* part = bufB;

    prep_kernel<<<BB * LL / 256, 256, 0, stream>>>(fg, mask, Sfg, Sbg, Qq);
    norm_kernel<<<BB * LL / 256, 256, 0, stream>>>(Sfg, Sbg, Qq, inorm, winv, SfgTap);

    for (int b = 0; b < BB; ++b) {
        const float* fgb = fg + (size_t)b * CC * LL;
        const float* mb = mask + (size_t)b * LL;
        ushort* bgHb = bgH + (size_t)b * CC * LL;
        int bofs = b * LL;

        transpose_kernel<<<dim3(64, 2), 256, 0, stream>>>(fgb, mb, fgT, bgT, bgHb);
        gemm_M_mfma<<<dim3(32, 32), 256, 0, stream>>>(bgT, fgT, M16);
        scoresbox_kernel<<<LL, 256, 0, stream>>>(M16, SfgTap, inorm, REB16, bofs);
        stats3_kernel<<<dim3(2, NCH), 256, 0, stream>>>(REB16, winv, sumc, wsumc, bofs);
        combine_ttap_kernel<<<64, 192, 0, stream>>>(sumc, wsumc, isum, Tp);
        ntile_kernel<<<8192, 256, 0, stream>>>(REB16, isum, NnT);
        gemm_out_part_mfma<<<dim3(64, KS), 256, 0, stream>>>(bgHb, NnT, part);
        epilogue_kernel<<<CC * LL / 256, 256, 0, stream>>>(part, Tp, fgb, mb, out + (size_t)b * CC * LL);
    }
}

// Round 12
// 644.645 us; speedup vs baseline: 1.7282x; 1.0010x over previous
//
#include <hip/hip_runtime.h>
#include <math.h>

#define BB 4
#define CC 128
#define HH 64
#define WW 64
#define LL 4096            // H*W
#define LL2 ((size_t)LL*LL)
#define EPSF 1e-7f
#define NCH 64             // softmax stats chunks over l
#define KS 8               // gemm_out k-slabs

typedef __attribute__((ext_vector_type(8))) short s8v;           // 8 bf16 (4 VGPRs)
typedef __attribute__((ext_vector_type(4))) float f4v;           // 4 fp32
typedef __attribute__((ext_vector_type(4))) unsigned short u4v;  // 4 bf16 (8B)
typedef __attribute__((ext_vector_type(8))) unsigned short u8v;  // 8 bf16 (16B)

struct f4u { float v[4]; };

__device__ __forceinline__ ushort f2bf(float f) {
    union { float f; unsigned u; } x; x.f = f;
    unsigned r = x.u + 0x7FFFu + ((x.u >> 16) & 1u);   // RNE
    return (ushort)(r >> 16);
}
__device__ __forceinline__ float bf2f(ushort u) {
    union { unsigned u; float f; } x; x.u = ((unsigned)u) << 16;
    return x.f;
}

// ---------- K1: per-position channel sums ----------
__global__ void prep_kernel(const float* __restrict__ fg, const float* __restrict__ mask,
                            float* __restrict__ Sfg, float* __restrict__ Sbg,
                            float* __restrict__ Qq) {
    int g = blockIdx.x * 256 + threadIdx.x;       // B*L threads
    int b = g >> 12, p = g & (LL - 1);
    float mval = mask[g];
    float s = 0.f, sb = 0.f, q = 0.f;
    const float* f = fg + (size_t)b * CC * LL + p;
    for (int c = 0; c < CC; ++c) {
        float v = f[(size_t)c * LL];
        s += v;
        float bv = v * (1.f - mval);
        sb += bv;
        q += bv * bv;
    }
    Sfg[g] = s; Sbg[g] = sb; Qq[g] = q;
}

// ---------- K2: inorm[l]=1/norm, winv[l]=norm, SfgTap[p]=valid-tap sum of Sfg ----------
__global__ void norm_kernel(const float* __restrict__ Sfg, const float* __restrict__ Sbg,
                            const float* __restrict__ Qq, float* __restrict__ inorm,
                            float* __restrict__ winv, float* __restrict__ SfgTap) {
    int g = blockIdx.x * 256 + threadIdx.x;       // B*L
    int b = g >> 12, l = g & (LL - 1);
    int i = l >> 6, j = l & 63;
    float n2 = 9.f * CC * EPSF * EPSF;
    float st = 0.f;
    for (int di = -1; di <= 1; ++di)
        for (int dj = -1; dj <= 1; ++dj) {
            int ii = i + di, jj = j + dj;
            if (ii >= 0 && ii < HH && jj >= 0 && jj < WW) {
                int idx = (b << 12) + (ii << 6) + jj;
                n2 += Qq[idx] + 2.f * EPSF * Sbg[idx];
                st += Sfg[idx];
            }
        }
    float n = sqrtf(n2);
    inorm[g] = 1.f / n;
    winv[g] = n;
    SfgTap[g] = st;
}

// ---------- K2b: per-sample bf16 copies: fgT/bgT [L][C] (transposed), bgH [C][L] ----------
__global__ __launch_bounds__(256) void transpose_kernel(const float* __restrict__ fgb,
                                                        const float* __restrict__ maskb,
                                                        ushort* __restrict__ fgT,
                                                        ushort* __restrict__ bgT,
                                                        ushort* __restrict__ bgH) {
    __shared__ float tile[64][65];
    int l0 = blockIdx.x * 64, c0 = blockIdx.y * 64;
    int tid = threadIdx.x, col = tid & 63, r0 = tid >> 6;
    for (int r = r0; r < 64; r += 4) {
        float v = fgb[(size_t)(c0 + r) * LL + l0 + col];
        tile[r][col] = v;
        bgH[(size_t)(c0 + r) * LL + l0 + col] = f2bf(v * (1.f - maskb[l0 + col]));
    }
    __syncthreads();
    for (int idx = tid; idx < 4096; idx += 256) {
        int row = idx >> 6;     // l offset
        int c = idx & 63;       // c offset
        float v = tile[c][row];
        size_t o = (size_t)(l0 + row) * CC + c0 + c;
        fgT[o] = f2bf(v);
        bgT[o] = f2bf(v * (1.f - maskb[l0 + row]));
    }
}

// ---------- K3: M (bf16) = bg^T @ fg via MFMA. A=bgT[L][C], B^T=fgT[L][C] ----------
__global__ __launch_bounds__(256) void gemm_M_mfma(const ushort* __restrict__ bgT,
                                                   const ushort* __restrict__ fgT,
                                                   ushort* __restrict__ M16) {
    int lt = blockIdx.y, pt = blockIdx.x;            // 32x32 tiles of 128x128
    int wid = threadIdx.x >> 6, lane = threadIdx.x & 63;
    int wm = wid >> 1, wn = wid & 1;                 // 2x2 waves
    int lm = lane & 15, lk = lane >> 4;
    f4v acc[4][4] = {};
    int arow = lt * 128 + wm * 64 + lm;
    int brow = pt * 128 + wn * 64 + lm;
    for (int k0 = 0; k0 < CC; k0 += 32) {
        s8v a[4], bq[4];
        #pragma unroll
        for (int f = 0; f < 4; ++f)
            a[f] = *(const s8v*)(bgT + (size_t)(arow + f * 16) * CC + k0 + lk * 8);
        #pragma unroll
        for (int f = 0; f < 4; ++f)
            bq[f] = *(const s8v*)(fgT + (size_t)(brow + f * 16) * CC + k0 + lk * 8);
        #pragma unroll
        for (int mi = 0; mi < 4; ++mi)
            #pragma unroll
            for (int ni = 0; ni < 4; ++ni)
                acc[mi][ni] = __builtin_amdgcn_mfma_f32_16x16x32_bf16(a[mi], bq[ni], acc[mi][ni], 0, 0, 0);
    }
    #pragma unroll
    for (int mi = 0; mi < 4; ++mi)
        #pragma unroll
        for (int ni = 0; ni < 4; ++ni)
            #pragma unroll
            for (int r = 0; r < 4; ++r)
                M16[(size_t)(lt * 128 + wm * 64 + mi * 16 + lk * 4 + r) * LL
                    + pt * 128 + wn * 64 + ni * 16 + lm] = f2bf(acc[mi][ni][r]);
}

// ---------- K4 v5: REB[l,:] (bf16). Pass1: 16B tap loads; Pass2: separable box ----------
__global__ __launch_bounds__(256) void scoresbox_kernel(const ushort* __restrict__ M16,
                                                        const float* __restrict__ SfgTap,
                                                        const float* __restrict__ inorm,
                                                        ushort* __restrict__ REB, int bofs) {
    __shared__ float srow[LL];   // 16 KB raw 9-tap diag sums
    __shared__ float cs[LL];     // 16 KB column (y) sums
    int l = blockIdx.x;
    int i = l >> 6, j = l & 63;
    float inl = inorm[bofs + l];
    float linl = __logf(inl);
    bool jm = (j >= 1), jp = (j <= 62);
    // pass 1: raw 9-tap diag sums (inl deferred; box is linear, inl block-constant)
    #pragma unroll
    for (int it = 0; it < 2; ++it) {
        int p8 = 8 * (threadIdx.x + it * 256);
        int y = p8 >> 6, x0 = p8 & 63;
        f4u t0 = *(const f4u*)(SfgTap + bofs + p8);
        f4u t1 = *(const f4u*)(SfgTap + bofs + p8 + 4);
        float acc[8];
        acc[0] = EPSF * t0.v[0]; acc[1] = EPSF * t0.v[1];
        acc[2] = EPSF * t0.v[2]; acc[3] = EPSF * t0.v[3];
        acc[4] = EPSF * t1.v[0]; acc[5] = EPSF * t1.v[1];
        acc[6] = EPSF * t1.v[2]; acc[7] = EPSF * t1.v[3];
        #pragma unroll
        for (int di = -1; di <= 1; ++di) {
            int ii = i + di, yy = y + di;
            if ((unsigned)ii >= HH || (unsigned)yy >= HH) continue;
            int rb = ii * 64;                       // row-block base
            size_t cb = (size_t)(p8 + di * 64);     // 16B-aligned col base
            {   // dj = 0
                const ushort* rw = M16 + (size_t)(rb + j) * LL + cb;
                u8v w = *(const u8v*)rw;
                #pragma unroll
                for (int k = 0; k < 8; ++k) acc[k] += bf2f(w[k]);
            }
            if (jm) {   // dj = -1: vals = [edge, w0..w6]
                const ushort* rw = M16 + (size_t)(rb + j - 1) * LL + cb;
                u8v w = *(const u8v*)rw;
                acc[0] += (x0 > 0) ? bf2f(rw[-1]) : 0.f;
                #pragma unroll
                for (int k = 1; k < 8; ++k) acc[k] += bf2f(w[k - 1]);
            }
            if (jp) {   // dj = +1: vals = [w1..w7, edge]
                const ushort* rw = M16 + (size_t)(rb + j + 1) * LL + cb;
                u8v w = *(const u8v*)rw;
                #pragma unroll
                for (int k = 0; k < 7; ++k) acc[k] += bf2f(w[k + 1]);
                acc[7] += (x0 < 56) ? bf2f(rw[8]) : 0.f;
            }
        }
        f4u o0, o1;
        o0.v[0] = acc[0]; o0.v[1] = acc[1]; o0.v[2] = acc[2]; o0.v[3] = acc[3];
        o1.v[0] = acc[4]; o1.v[1] = acc[5]; o1.v[2] = acc[6]; o1.v[3] = acc[7];
        *(f4u*)(srow + p8) = o0;
        *(f4u*)(srow + p8 + 4) = o1;
    }
    __syncthreads();
    // pass 2a: column (y) sums, vectorized
    #pragma unroll
    for (int it = 0; it < 4; ++it) {
        int p4 = 4 * (threadIdx.x + it * 256);
        int y = p4 >> 6, x0 = p4 & 63;
        f4v a = {0.f, 0.f, 0.f, 0.f};
        #pragma unroll
        for (int gy = -1; gy <= 1; ++gy) {
            int yy = y + gy;
            if ((unsigned)yy >= HH) continue;
            a += *(const f4v*)&srow[(yy << 6) + x0];
        }
        *(f4v*)&cs[p4] = a;
    }
    __syncthreads();
    // pass 2b: horizontal (x) sums + exp, vectorized
    #pragma unroll
    for (int it = 0; it < 4; ++it) {
        int p4 = 4 * (threadIdx.x + it * 256);
        int x0 = p4 & 63;
        f4v c = *(const f4v*)&cs[p4];
        float lm = (x0 > 0) ? cs[p4 - 1] : 0.f;
        float rm = (x0 < 60) ? cs[p4 + 4] : 0.f;
        float b0 = lm + c[0] + c[1];
        float b1 = c[0] + c[1] + c[2];
        float b2 = c[1] + c[2] + c[3];
        float b3 = c[2] + c[3] + rm;
        u4v o;
        o[0] = f2bf(__expf(fmaf(b0, inl, linl)));
        o[1] = f2bf(__expf(fmaf(b1, inl, linl)));
        o[2] = f2bf(__expf(fmaf(b2, inl, linl)));
        o[3] = f2bf(__expf(fmaf(b3, inl, linl)));
        *(u4v*)(REB + (size_t)l * LL + p4) = o;
    }
}

// ---------- K5: plain column sums over bf16 REB: sumc=Σ REB*winv, wsumc=Σ REB ----------
__global__ __launch_bounds__(256) void stats3_kernel(const ushort* __restrict__ REB,
                                                     const float* __restrict__ winv,
                                                     float* __restrict__ sumc,
                                                     float* __restrict__ wsumc, int bofs) {
    int pt = blockIdx.x, ch = blockIdx.y;
    int p = pt * 2048 + threadIdx.x * 8;
    float s[8] = {}, w[8] = {};
    int l0 = ch * (LL / NCH);
    for (int l = l0; l < l0 + LL / NCH; ++l) {
        u4v h0 = *(const u4v*)(REB + (size_t)l * LL + p);
        u4v h1 = *(const u4v*)(REB + (size_t)l * LL + p + 4);
        float wv = winv[bofs + l];
        float v0 = bf2f(h0[0]), v1 = bf2f(h0[1]), v2 = bf2f(h0[2]), v3 = bf2f(h0[3]);
        float v4 = bf2f(h1[0]), v5 = bf2f(h1[1]), v6 = bf2f(h1[2]), v7 = bf2f(h1[3]);
        w[0] += v0; w[1] += v1; w[2] += v2; w[3] += v3;
        w[4] += v4; w[5] += v5; w[6] += v6; w[7] += v7;
        s[0] += v0 * wv; s[1] += v1 * wv; s[2] += v2 * wv; s[3] += v3 * wv;
        s[4] += v4 * wv; s[5] += v5 * wv; s[6] += v6 * wv; s[7] += v7 * wv;
    }
    int idx = ch * LL + p;
    #pragma unroll
    for (int h = 0; h < 2; ++h) {
        f4u so, wo;
        #pragma unroll
        for (int k = 0; k < 4; ++k) { so.v[k] = s[h * 4 + k]; wo.v[k] = w[h * 4 + k]; }
        *(f4u*)(sumc + idx + h * 4) = so;
        *(f4u*)(wsumc + idx + h * 4) = wo;
    }
}

// ---------- K5b: combine chunk sums: isum[p]=1/sumexp; Tp = box(wsum*isum) ----------
__global__ __launch_bounds__(192) void combine_ttap_kernel(const float* __restrict__ sumc,
                                                           const float* __restrict__ wsumc,
                                                           float* __restrict__ isum,
                                                           float* __restrict__ Tp) {
    __shared__ float bs[3][64];
    int yb = blockIdx.x;
    int t = threadIdx.x;              // 0..191
    int r = t >> 6, xcol = t & 63;    // r: row offset (yb-1+r)
    int yy = yb - 1 + r;
    float bv = 0.f;
    if ((unsigned)yy < HH) {
        int p = (yy << 6) + xcol;
        float se = 0.f, ws = 0.f;
        for (int ch = 0; ch < NCH; ++ch) {
            int idx = ch * LL + p;
            se += sumc[idx];
            ws += wsumc[idx];
        }
        float inv = 1.f / se;
        if (r == 1) isum[p] = inv;
        bv = ws * inv;
    }
    bs[r][xcol] = bv;
    __syncthreads();
    if (r == 1) {
        float tt = 0.f;
        #pragma unroll
        for (int rr = 0; rr < 3; ++rr) {
            tt += bs[rr][xcol];
            if (xcol > 0) tt += bs[rr][xcol - 1];
            if (xcol < 63) tt += bs[rr][xcol + 1];
        }
        Tp[(yb << 6) + xcol] = tt;
    }
}

// ---------- K7 v3: fused 9-tap diag stencil + transpose, bf16 LDS for 8 blocks/CU ----------
__global__ __launch_bounds__(256, 8) void ntile_kernel(const ushort* __restrict__ REB,
                                                       const float* __restrict__ isum,
                                                       ushort* __restrict__ NnT) {
    __shared__ ushort bandH[3][34][68];  // 13.9 KB (row pitch 136B, 8B-aligned)
    __shared__ ushort T[64][36];         // 4.5 KB
    int bid = blockIdx.x;
    int jh = bid & 1;            // j-half
    int y = (bid >> 1) & 63;     // p spatial row
    int i = bid >> 7;            // l spatial row
    int j0 = jh * 32;
    int tid = threadIdx.x;

    #pragma unroll
    for (int di = -1; di <= 1; ++di) {
        int ii = i + di, yy = y + di;
        ushort* dstB = &bandH[di + 1][0][0];
        if ((unsigned)ii >= 64u || (unsigned)yy >= 64u) {
            for (int idx = tid; idx < 34 * 68 / 4; idx += 256) {
                u4v z = {0, 0, 0, 0};
                *(u4v*)(dstB + idx * 4) = z;
            }
            continue;
        }
        const ushort* src = REB + ((size_t)ii * 64) * LL + yy * 64;
        const float* isrc = isum + yy * 64;
        for (int idx = tid; idx < 34 * 8; idx += 256) {
            int r = idx >> 3, cg = (idx & 7) * 8;
            ushort* dst = &bandH[di + 1][r][cg];
            int jg = j0 - 1 + r;            // global j row
            if ((unsigned)jg < 64u) {
                u4v h0 = *(const u4v*)(src + (size_t)jg * LL + cg);
                u4v h1 = *(const u4v*)(src + (size_t)jg * LL + cg + 4);
                f4u w0 = *(const f4u*)(isrc + cg);
                f4u w1 = *(const f4u*)(isrc + cg + 4);
                u4v o0, o1;
                o0[0] = f2bf(bf2f(h0[0]) * w0.v[0]);
                o0[1] = f2bf(bf2f(h0[1]) * w0.v[1]);
                o0[2] = f2bf(bf2f(h0[2]) * w0.v[2]);
                o0[3] = f2bf(bf2f(h0[3]) * w0.v[3]);
                o1[0] = f2bf(bf2f(h1[0]) * w1.v[0]);
                o1[1] = f2bf(bf2f(h1[1]) * w1.v[1]);
                o1[2] = f2bf(bf2f(h1[2]) * w1.v[2]);
                o1[3] = f2bf(bf2f(h1[3]) * w1.v[3]);
                *(u4v*)dst = o0;
                *(u4v*)(dst + 4) = o1;
            } else {
                u4v z = {0, 0, 0, 0};
                *(u4v*)dst = z;
                *(u4v*)(dst + 4) = z;
            }
        }
    }
    __syncthreads();

    int x = tid & 63, jb = tid >> 6;
    bool xm1 = (x >= 1), xp1 = (x <= 62);
    float accv[8];
    #pragma unroll
    for (int k = 0; k < 8; ++k) accv[k] = 0.f;
    #pragma unroll
    for (int d3 = 0; d3 < 3; ++d3) {
        const ushort (*B)[68] = bandH[d3];
        #pragma unroll
        for (int k = 0; k < 8; ++k) {
            int jl = jb * 8 + k;       // 0..31
            int j = j0 + jl;           // global j
            int rc = jl + 1;           // band row of center tap
            float s = bf2f(B[rc][x]);
            if (xm1 && j >= 1)  s += bf2f(B[rc - 1][x - 1]);
            if (xp1 && j <= 62) s += bf2f(B[rc + 1][x + 1]);
            accv[k] += s;
        }
    }
    #pragma unroll
    for (int k = 0; k < 8; ++k)
        T[x][jb * 8 + k] = f2bf(accv[k]);
    __syncthreads();

    int xr = tid >> 2, q4 = tid & 3;
    size_t obase = (size_t)(y * 64 + xr) * LL + i * 64 + j0 + q4 * 8;
    u4v v0 = *(const u4v*)&T[xr][q4 * 8];
    u4v v1 = *(const u4v*)&T[xr][q4 * 8 + 4];
    *(u4v*)(NnT + obase) = v0;
    *(u4v*)(NnT + obase + 4) = v1;
}

// ---------- K9a: partial rec = bgH @ NnT^T over a k-slab, MFMA ----------
__global__ __launch_bounds__(256) void gemm_out_part_mfma(const ushort* __restrict__ bgH,
                                                          const ushort* __restrict__ NnT,
                                                          float* __restrict__ part) {
    int pt = blockIdx.x, ks = blockIdx.y;
    int wid = threadIdx.x >> 6, lane = threadIdx.x & 63;
    int wm = wid >> 1, wn = wid & 1;
    int lm = lane & 15, lk = lane >> 4;
    f4v acc[4][2] = {};
    int arow = wm * 64 + lm;          // c
    int brow = pt * 64 + wn * 32 + lm; // p
    int kbeg = ks * (LL / KS);
    #pragma unroll 2
    for (int k0 = kbeg; k0 < kbeg + LL / KS; k0 += 32) {
        s8v a[4], bq[2];
        #pragma unroll
        for (int f = 0; f < 4; ++f)
            a[f] = *(const s8v*)(bgH + (size_t)(arow + f * 16) * LL + k0 + lk * 8);
        #pragma unroll
        for (int f = 0; f < 2; ++f)
            bq[f] = *(const s8v*)(NnT + (size_t)(brow + f * 16) * LL + k0 + lk * 8);
        #pragma unroll
        for (int mi = 0; mi < 4; ++mi)
            #pragma unroll
            for (int ni = 0; ni < 2; ++ni)
                acc[mi][ni] = __builtin_amdgcn_mfma_f32_16x16x32_bf16(a[mi], bq[ni], acc[mi][ni], 0, 0, 0);
    }
    #pragma unroll
    for (int mi = 0; mi < 4; ++mi)
        #pragma unroll
        for (int ni = 0; ni < 2; ++ni)
            #pragma unroll
            for (int r = 0; r < 4; ++r)
                part[((size_t)ks * CC + wm * 64 + mi * 16 + lk * 4 + r) * LL
                     + pt * 64 + wn * 32 + ni * 16 + lm] = acc[mi][ni][r];
}

// ---------- K9b: combine slabs + epilogue ----------
__global__ void epilogue_kernel(const float* __restrict__ part, const float* __restrict__ Tp,
                                const float* __restrict__ fgb, const float* __restrict__ maskb,
                                float* __restrict__ outb) {
    int g = blockIdx.x * 256 + threadIdx.x;   // C*L
    int p = g & 4095;
    float acc = 0.f;
    for (int ks = 0; ks < KS; ++ks)
        acc += part[(size_t)ks * CC * LL + g];
    float rec = acc + EPSF * Tp[p];
    float mval = maskb[p];
    outb[g] = rec * mval * (1.f / 9.f) + fgb[g] * (1.f - mval);
}

extern "C" void kernel_launch(void* const* d_in, const int* in_sizes, int n_in,
                              void* d_out, int out_size, void* d_ws, size_t ws_size,
                              hipStream_t stream) {
    const float* fg = (const float*)d_in[0];     // [B,C,H,W]
    const float* mask = (const float*)d_in[1];   // [B,1,H,W]
    float* out = (float*)d_out;
    float* ws = (float*)d_ws;

    // ws layout (~134.5 MiB)
    float* Sfg = ws;                                 // B*LL each:
    float* Sbg = Sfg + BB * LL;
    float* Qq = Sbg + BB * LL;
    float* inorm = Qq + BB * LL;
    float* winv = inorm + BB * LL;
    float* SfgTap = winv + BB * LL;
    float* sumc = SfgTap + BB * LL;                  // NCH*LL each:
    float* wsumc = sumc + NCH * LL;
    float* isum = wsumc + NCH * LL;                  // LL each:
    float* Tp = isum + LL;
    ushort* bgH = (ushort*)(Tp + LL);                // B*CC*LL ushorts (4 MiB)
    float* bufA = (float*)(bgH + (size_t)BB * CC * LL);   // LL2 (M16, then NnT)
    float* bufB = bufA + LL2;                        // LL2 (REB16 in first half, then part)
    // per-sample transposed bf16 operand tiles live in bufB tail (dead until scoresbox):
    ushort* bgT = (ushort*)(bufB + 8 * 1024 * 1024);
    ushort* fgT = bgT + (size_t)LL * CC;
    // M bf16 occupies first 32 MB of bufA; NnT reuses the same region after scoresbox:
    ushort* M16 = (ushort*)bufA;
    ushort* NnT = (ushort*)bufA;
    // REB bf16 occupies first 32 MB of bufB:
    ushort* REB16 = (ushort*)bufB;
    // after ntile, REB16 (bufB) is dead -> reuse for fp32 partials (16 MB):
    float* part = bufB;

    prep_kernel<<<BB * LL / 256, 256, 0, stream>>>(fg, mask, Sfg, Sbg, Qq);
    norm_kernel<<<BB * LL / 256, 256, 0, stream>>>(Sfg, Sbg, Qq, inorm, winv, SfgTap);

    for (int b = 0; b < BB; ++b) {
        const float* fgb = fg + (size_t)b * CC * LL;
        const float* mb = mask + (size_t)b * LL;
        ushort* bgHb = bgH + (size_t)b * CC * LL;
        int bofs = b * LL;

        transpose_kernel<<<dim3(64, 2), 256, 0, stream>>>(fgb, mb, fgT, bgT, bgHb);
        gemm_M_mfma<<<dim3(32, 32), 256, 0, stream>>>(bgT, fgT, M16);
        scoresbox_kernel<<<LL, 256, 0, stream>>>(M16, SfgTap, inorm, REB16, bofs);
        stats3_kernel<<<dim3(2, NCH), 256, 0, stream>>>(REB16, winv, sumc, wsumc, bofs);
        combine_ttap_kernel<<<64, 192, 0, stream>>>(sumc, wsumc, isum, Tp);
        ntile_kernel<<<8192, 256, 0, stream>>>(REB16, isum, NnT);
        gemm_out_part_mfma<<<dim3(64, KS), 256, 0, stream>>>(bgHb, NnT, part);
        epilogue_kernel<<<CC * LL / 256, 256, 0, stream>>>(part, Tp, fgb, mb, out + (size_t)b * CC * LL);
    }
}